// Round 1
// baseline (13476.897 us; speedup 1.0000x reference)
//
#include <hip/hip_runtime.h>
#include <hip/hip_bf16.h>
#include <math.h>

// Problem constants (fixed by the reference)
#define GN 100000   // nodes
#define GE 1200000  // edges
#define GB 128      // graphs
#define GF 92       // raw features
#define GD 64       // hidden dim
#define GL 3        // CGConv layers
#define GZ 129      // 2*D+1

// ---------------------------------------------------------------------------
// Generic dense layer: out[n,d] = relu(in[n,:K] @ W[K,64] + b[d])
// Thread = (node, d) with d = idx&63 -> within a 64-lane wave, `node` is
// uniform, so in-row reads become scalar loads; W reads are coalesced.
// ---------------------------------------------------------------------------
__global__ __launch_bounds__(256) void mlp_kernel(
    const float* __restrict__ in, const float* __restrict__ W,
    const float* __restrict__ b, float* __restrict__ out,
    int N, int K, int do_relu)
{
    int idx = blockIdx.x * blockDim.x + threadIdx.x;
    int node = idx >> 6;
    int d = idx & 63;
    if (node >= N) return;
    const float* __restrict__ row = in + (size_t)node * K;
    float acc = b[d];
    for (int k = 0; k < K; ++k)
        acc = fmaf(row[k], W[k * 64 + d], acc);
    if (do_relu) acc = fmaxf(acc, 0.f);
    out[(size_t)node * 64 + d] = acc;
}

// ---------------------------------------------------------------------------
// In-degree histogram (float) for mean aggregation
// ---------------------------------------------------------------------------
__global__ __launch_bounds__(256) void deg_kernel(
    const int* __restrict__ dst, float* __restrict__ deg, int E)
{
    int e = blockIdx.x * blockDim.x + threadIdx.x;
    if (e < E) atomicAdd(&deg[dst[e]], 1.0f);
}

// ---------------------------------------------------------------------------
// CGConv gate: per edge e,
//   z = [h[dst] || h[src] || ea]  (129)
//   m[d] = sigmoid(z.Wf[:,d]+bf[d]) * softplus(z.Ws[:,d]+bs[d])
//   agg[dst,d] += m[d]   (atomic)
// One thread per edge; two 32-wide output halves to bound VGPR use.
// Weight addresses are wave-uniform -> scalar loads + SGPR-operand FMAs.
// ---------------------------------------------------------------------------
__global__ __launch_bounds__(256) void gate_kernel(
    const float* __restrict__ h,
    const int* __restrict__ src, const int* __restrict__ dst,
    const float* __restrict__ ea,
    const float* __restrict__ Wf, const float* __restrict__ bf,
    const float* __restrict__ Ws, const float* __restrict__ bs,
    float* __restrict__ agg, int E)
{
    int e = blockIdx.x * blockDim.x + threadIdx.x;
    if (e >= E) return;
    int s = src[e];
    int d = dst[e];
    float eav = ea[e];
    const float4* __restrict__ hd4 = (const float4*)(h + (size_t)d * 64);
    const float4* __restrict__ hs4 = (const float4*)(h + (size_t)s * 64);
    float* __restrict__ aggRow = agg + (size_t)d * 64;

    for (int half = 0; half < 2; ++half) {
        const float* __restrict__ WfH = Wf + half * 32;
        const float* __restrict__ WsH = Ws + half * 32;
        float aF[32], aS[32];
#pragma unroll
        for (int j = 0; j < 32; ++j) { aF[j] = 0.f; aS[j] = 0.f; }

        // k = 0..63 : h[dst]
        for (int c = 0; c < 16; ++c) {
            float4 z4 = hd4[c];
#pragma unroll
            for (int i = 0; i < 4; ++i) {
                float zk = (i == 0) ? z4.x : (i == 1) ? z4.y : (i == 2) ? z4.z : z4.w;
                const float* __restrict__ w1 = WfH + (c * 4 + i) * 64;
                const float* __restrict__ w2 = WsH + (c * 4 + i) * 64;
#pragma unroll
                for (int j = 0; j < 32; ++j) {
                    aF[j] = fmaf(zk, w1[j], aF[j]);
                    aS[j] = fmaf(zk, w2[j], aS[j]);
                }
            }
        }
        // k = 64..127 : h[src]
        for (int c = 0; c < 16; ++c) {
            float4 z4 = hs4[c];
#pragma unroll
            for (int i = 0; i < 4; ++i) {
                float zk = (i == 0) ? z4.x : (i == 1) ? z4.y : (i == 2) ? z4.z : z4.w;
                const float* __restrict__ w1 = WfH + (64 + c * 4 + i) * 64;
                const float* __restrict__ w2 = WsH + (64 + c * 4 + i) * 64;
#pragma unroll
                for (int j = 0; j < 32; ++j) {
                    aF[j] = fmaf(zk, w1[j], aF[j]);
                    aS[j] = fmaf(zk, w2[j], aS[j]);
                }
            }
        }
        // k = 128 : edge attr
        {
            const float* __restrict__ w1 = WfH + 128 * 64;
            const float* __restrict__ w2 = WsH + 128 * 64;
#pragma unroll
            for (int j = 0; j < 32; ++j) {
                aF[j] = fmaf(eav, w1[j], aF[j]);
                aS[j] = fmaf(eav, w2[j], aS[j]);
            }
        }
        // epilogue: activations + atomic scatter
#pragma unroll
        for (int j = 0; j < 32; ++j) {
            float xF = aF[j] + bf[half * 32 + j];
            float xS = aS[j] + bs[half * 32 + j];
            float sig = 1.f / (1.f + __expf(-xF));
            float sp = fmaxf(xS, 0.f) + log1pf(__expf(-fabsf(xS)));
            atomicAdd(aggRow + half * 32 + j, sig * sp);
        }
    }
}

// ---------------------------------------------------------------------------
// Residual update: h = relu(h + agg/denom), denom = max(deg,1)
// ---------------------------------------------------------------------------
__global__ __launch_bounds__(256) void update_kernel(
    float* __restrict__ h, const float* __restrict__ agg,
    const float* __restrict__ deg, int N)
{
    int idx = blockIdx.x * blockDim.x + threadIdx.x;
    int node = idx >> 6;
    if (node >= N) return;
    float dn = fmaxf(deg[node], 1.f);
    h[idx] = fmaxf(h[idx] + agg[idx] / dn, 0.f);
}

// ---------------------------------------------------------------------------
// Global mean pool: scatter-add node features + counts per graph
// ---------------------------------------------------------------------------
__global__ __launch_bounds__(256) void pool_kernel(
    const float* __restrict__ h, const int* __restrict__ bm,
    float* __restrict__ gsum, float* __restrict__ cnt, int N)
{
    int idx = blockIdx.x * blockDim.x + threadIdx.x;
    int node = idx >> 6;
    int d = idx & 63;
    if (node >= N) return;
    int b = bm[node];   // wave-uniform
    atomicAdd(&gsum[(size_t)b * 64 + d], h[idx]);
    if (d == 0) atomicAdd(&cnt[b], 1.f);
}

__global__ __launch_bounds__(256) void pooldiv_kernel(
    float* __restrict__ g, const float* __restrict__ cnt, int B)
{
    int idx = blockIdx.x * blockDim.x + threadIdx.x;
    if (idx >= B * 64) return;
    int b = idx >> 6;
    g[idx] = g[idx] / fmaxf(cnt[b], 1.f);
}

// ---------------------------------------------------------------------------
// Final projection: out[b] = g[b,:] . Wf + bf
// ---------------------------------------------------------------------------
__global__ __launch_bounds__(128) void final_kernel(
    const float* __restrict__ g, const float* __restrict__ Wf,
    const float* __restrict__ bf, float* __restrict__ out, int B)
{
    int b = blockIdx.x * blockDim.x + threadIdx.x;
    if (b >= B) return;
    float acc = bf[0];
#pragma unroll
    for (int k = 0; k < 64; ++k)
        acc = fmaf(g[(size_t)b * 64 + k], Wf[k], acc);
    out[b] = acc;
}

extern "C" void kernel_launch(void* const* d_in, const int* in_sizes, int n_in,
                              void* d_out, int out_size, void* d_ws, size_t ws_size,
                              hipStream_t stream)
{
    const float* X      = (const float*)d_in[0];
    const int*   eidx   = (const int*)d_in[1];
    const float* ea     = (const float*)d_in[3];
    const int*   bm     = (const int*)d_in[4];
    const float* pre_W0 = (const float*)d_in[5];
    const float* pre_b0 = (const float*)d_in[6];
    const float* pre_W1 = (const float*)d_in[7];
    const float* pre_b1 = (const float*)d_in[8];
    const float* pre_W2 = (const float*)d_in[9];
    const float* pre_b2 = (const float*)d_in[10];
    const float* cg_Wf  = (const float*)d_in[11];
    const float* cg_bf  = (const float*)d_in[12];
    const float* cg_Ws  = (const float*)d_in[13];
    const float* cg_bs  = (const float*)d_in[14];
    const float* post_W0 = (const float*)d_in[15];
    const float* post_b0 = (const float*)d_in[16];
    const float* post_W1 = (const float*)d_in[17];
    const float* post_b1 = (const float*)d_in[18];
    const float* post_W2 = (const float*)d_in[19];
    const float* post_b2 = (const float*)d_in[20];
    const float* post_Wf = (const float*)d_in[21];
    const float* post_bf = (const float*)d_in[22];

    const int* src = eidx;        // edge_idx[0]
    const int* dst = eidx + GE;   // edge_idx[1]

    // workspace carve-up (floats)
    float* hA  = (float*)d_ws;            // N*64
    float* hB  = hA + (size_t)GN * 64;    // N*64 (agg / mlp temp)
    float* deg = hB + (size_t)GN * 64;    // N
    float* g0  = deg + GN;                // B*64
    float* g1  = g0 + GB * 64;            // B*64
    float* cnt = g1 + GB * 64;            // B

    const int TPB = 256;
    int gridND = (GN * 64 + TPB - 1) / TPB;
    int gridE  = (GE + TPB - 1) / TPB;
    int gridBD = (GB * 64 + TPB - 1) / TPB;

    // pre-GC MLP: X(F)->hA, hA->hB, hB->hA
    mlp_kernel<<<gridND, TPB, 0, stream>>>(X,  pre_W0, pre_b0, hA, GN, GF, 1);
    mlp_kernel<<<gridND, TPB, 0, stream>>>(hA, pre_W1, pre_b1, hB, GN, GD, 1);
    mlp_kernel<<<gridND, TPB, 0, stream>>>(hB, pre_W2, pre_b2, hA, GN, GD, 1);

    // degrees
    hipMemsetAsync(deg, 0, GN * sizeof(float), stream);
    deg_kernel<<<gridE, TPB, 0, stream>>>(dst, deg, GE);

    // CGConv layers
    for (int l = 0; l < GL; ++l) {
        hipMemsetAsync(hB, 0, (size_t)GN * 64 * sizeof(float), stream);
        gate_kernel<<<gridE, TPB, 0, stream>>>(
            hA, src, dst, ea,
            cg_Wf + (size_t)l * GZ * GD, cg_bf + (size_t)l * GD,
            cg_Ws + (size_t)l * GZ * GD, cg_bs + (size_t)l * GD,
            hB, GE);
        update_kernel<<<gridND, TPB, 0, stream>>>(hA, hB, deg, GN);
    }

    // global mean pool
    hipMemsetAsync(g0, 0, GB * 64 * sizeof(float), stream);
    hipMemsetAsync(cnt, 0, GB * sizeof(float), stream);
    pool_kernel<<<gridND, TPB, 0, stream>>>(hA, bm, g0, cnt, GN);
    pooldiv_kernel<<<gridBD, TPB, 0, stream>>>(g0, cnt, GB);

    // post-GC MLP
    mlp_kernel<<<gridBD, TPB, 0, stream>>>(g0, post_W0, post_b0, g1, GB, GD, 1);
    mlp_kernel<<<gridBD, TPB, 0, stream>>>(g1, post_W1, post_b1, g0, GB, GD, 1);
    mlp_kernel<<<gridBD, TPB, 0, stream>>>(g0, post_W2, post_b2, g1, GB, GD, 1);
    final_kernel<<<1, 128, 0, stream>>>(g1, post_Wf, post_bf, (float*)d_out, GB);
}

// Round 2
// 3499.223 us; speedup vs baseline: 3.8514x; 3.8514x over previous
//
#include <hip/hip_runtime.h>
#include <hip/hip_bf16.h>
#include <math.h>

// Problem constants (fixed by the reference)
#define GN 100000   // nodes
#define GE 1200000  // edges
#define GB 128      // graphs
#define GF 92       // raw features
#define GD 64       // hidden dim
#define GL 3        // CGConv layers
#define GZ 129      // 2*D+1

// ---------------------------------------------------------------------------
// Dense layer, one node per 64-thread block: out[n,d] = relu(in[n,:K]@W[:,d]+b[d])
// blockIdx-derived row pointer -> provably wave-uniform -> s_load stream;
// W[k*64+d] coalesced across lanes.
// ---------------------------------------------------------------------------
__global__ __launch_bounds__(64) void mlp64_kernel(
    const float* __restrict__ in, const float* __restrict__ W,
    const float* __restrict__ b, float* __restrict__ out, int K)
{
    int n = blockIdx.x;
    int d = threadIdx.x;
    const float* __restrict__ row = in + (size_t)n * K;
    float acc = b[d];
    for (int k = 0; k < K; ++k)
        acc = fmaf(row[k], W[k * 64 + d], acc);
    out[(size_t)n * 64 + d] = fmaxf(acc, 0.f);
}

// ---------------------------------------------------------------------------
// In-degree histogram (int)
// ---------------------------------------------------------------------------
__global__ __launch_bounds__(256) void deg_kernel(
    const int* __restrict__ dst, int* __restrict__ deg, int E)
{
    int e = blockIdx.x * blockDim.x + threadIdx.x;
    if (e < E) atomicAdd(&deg[dst[e]], 1);
}

// ---------------------------------------------------------------------------
// Three-phase exclusive scan over deg -> rowptr, cursor
// ---------------------------------------------------------------------------
__global__ __launch_bounds__(1024) void scanA_kernel(
    const int* __restrict__ deg, int* __restrict__ iscan,
    int* __restrict__ bsum, int N)
{
    __shared__ int lds[1024];
    int tid = threadIdx.x;
    int gid = blockIdx.x * 1024 + tid;
    int v = (gid < N) ? deg[gid] : 0;
    lds[tid] = v; __syncthreads();
    for (int off = 1; off < 1024; off <<= 1) {
        int t = (tid >= off) ? lds[tid - off] : 0;
        __syncthreads();
        lds[tid] += t;
        __syncthreads();
    }
    if (gid < N) iscan[gid] = lds[tid];
    if (tid == 1023) bsum[blockIdx.x] = lds[1023];
}

__global__ __launch_bounds__(128) void scanB_kernel(
    const int* __restrict__ bsum, int* __restrict__ boff, int nb)
{
    __shared__ int lds[128];
    int t = threadIdx.x;
    int v = (t < nb) ? bsum[t] : 0;
    lds[t] = v; __syncthreads();
    for (int off = 1; off < 128; off <<= 1) {
        int u = (t >= off) ? lds[t - off] : 0;
        __syncthreads();
        lds[t] += u;
        __syncthreads();
    }
    if (t < nb) boff[t] = lds[t] - v;  // exclusive
}

__global__ __launch_bounds__(256) void scanC_kernel(
    const int* __restrict__ iscan, const int* __restrict__ boff,
    const int* __restrict__ deg,
    int* __restrict__ rowptr, int* __restrict__ cursor, int N)
{
    int i = blockIdx.x * blockDim.x + threadIdx.x;
    if (i >= N) return;
    int incl = iscan[i] + boff[i >> 10];
    rowptr[i + 1] = incl;
    cursor[i] = incl - deg[i];
    if (i == 0) rowptr[0] = 0;
}

// ---------------------------------------------------------------------------
// Degree-bucket ordering (equal-degree nodes adjacent -> no wave divergence)
// ---------------------------------------------------------------------------
__global__ __launch_bounds__(256) void bhist_kernel(
    const int* __restrict__ deg, int* __restrict__ bcnt, int N)
{
    int n = blockIdx.x * blockDim.x + threadIdx.x;
    if (n < N) atomicAdd(&bcnt[min(deg[n], 63)], 1);
}

__global__ __launch_bounds__(64) void bscan_kernel(
    const int* __restrict__ bcnt, int* __restrict__ bcur)
{
    __shared__ int lds[64];
    int t = threadIdx.x;
    int v = bcnt[t];
    lds[t] = v; __syncthreads();
    for (int off = 1; off < 64; off <<= 1) {
        int u = (t >= off) ? lds[t - off] : 0;
        __syncthreads();
        lds[t] += u;
        __syncthreads();
    }
    bcur[t] = lds[t] - v;  // exclusive start
}

__global__ __launch_bounds__(256) void bscatter_kernel(
    const int* __restrict__ deg, int* __restrict__ bcur,
    int* __restrict__ node_order, int N)
{
    int n = blockIdx.x * blockDim.x + threadIdx.x;
    if (n >= N) return;
    int pos = atomicAdd(&bcur[min(deg[n], 63)], 1);
    node_order[pos] = n;
}

// ---------------------------------------------------------------------------
// Edge scatter into CSR order: e_src/e_ea sorted by dst
// ---------------------------------------------------------------------------
__global__ __launch_bounds__(256) void escatter_kernel(
    const int* __restrict__ src, const int* __restrict__ dst,
    const float* __restrict__ ea, int* __restrict__ cursor,
    int* __restrict__ e_src, float* __restrict__ e_ea, int E)
{
    int e = blockIdx.x * blockDim.x + threadIdx.x;
    if (e >= E) return;
    int pos = atomicAdd(&cursor[dst[e]], 1);
    e_src[pos] = src[e];
    e_ea[pos] = ea[e];
}

// ---------------------------------------------------------------------------
// CGConv, pull form. Thread = (node, 16-wide output quarter).
// quarter = blockIdx&3 (block-uniform -> weight loads are s_load streams,
// shared by all 64 lanes in lockstep over their edge lists).
// Per node: base = bias + h[dst]@W[0:64] computed once; per edge only the
// h[src]@W[64:128] + ea*W[128] part. Residual+relu+mean fused at the end.
// ---------------------------------------------------------------------------
__global__ __launch_bounds__(256) void gate_pull_kernel(
    const float* __restrict__ h, const int* __restrict__ rowptr,
    const int* __restrict__ e_src, const float* __restrict__ e_ea,
    const int* __restrict__ node_order,
    const float* __restrict__ Wf, const float* __restrict__ bfv,
    const float* __restrict__ Ws, const float* __restrict__ bsv,
    float* __restrict__ hout)
{
    const int q = blockIdx.x & 3;   // block-uniform output quarter
    int slot = (blockIdx.x >> 2) * 256 + threadIdx.x;
    bool act = slot < GN;
    int n = act ? node_order[slot] : 0;
    int rb = rowptr[n];
    int re = act ? rowptr[n + 1] : rb;

    const float* __restrict__ Wfq = Wf + q * 16;
    const float* __restrict__ Wsq = Ws + q * 16;

    // base: bias + h[dst] part (once per node)
    float bF[16], bS[16];
#pragma unroll
    for (int j = 0; j < 16; ++j) { bF[j] = bfv[q * 16 + j]; bS[j] = bsv[q * 16 + j]; }
    const float4* __restrict__ hd4 = (const float4*)(h + (size_t)n * 64);
#pragma unroll 4
    for (int c = 0; c < 16; ++c) {
        float4 v = hd4[c];
#pragma unroll
        for (int i = 0; i < 4; ++i) {
            float zk = (i == 0) ? v.x : (i == 1) ? v.y : (i == 2) ? v.z : v.w;
            const float* __restrict__ w1 = Wfq + (c * 4 + i) * 64;
            const float* __restrict__ w2 = Wsq + (c * 4 + i) * 64;
#pragma unroll
            for (int j = 0; j < 16; ++j) {
                bF[j] = fmaf(zk, w1[j], bF[j]);
                bS[j] = fmaf(zk, w2[j], bS[j]);
            }
        }
    }

    float agg[16];
#pragma unroll
    for (int j = 0; j < 16; ++j) agg[j] = 0.f;

    for (int p = rb; p < re; ++p) {
        int s = e_src[p];
        float eav = e_ea[p];
        const float4* __restrict__ hs4 = (const float4*)(h + (size_t)s * 64);
        float xF[16], xS[16];
#pragma unroll
        for (int j = 0; j < 16; ++j) {
            xF[j] = fmaf(eav, Wfq[128 * 64 + j], bF[j]);
            xS[j] = fmaf(eav, Wsq[128 * 64 + j], bS[j]);
        }
#pragma unroll 4
        for (int c = 0; c < 16; ++c) {
            float4 v = hs4[c];
#pragma unroll
            for (int i = 0; i < 4; ++i) {
                float zk = (i == 0) ? v.x : (i == 1) ? v.y : (i == 2) ? v.z : v.w;
                const float* __restrict__ w1 = Wfq + (64 + c * 4 + i) * 64;
                const float* __restrict__ w2 = Wsq + (64 + c * 4 + i) * 64;
#pragma unroll
                for (int j = 0; j < 16; ++j) {
                    xF[j] = fmaf(zk, w1[j], xF[j]);
                    xS[j] = fmaf(zk, w2[j], xS[j]);
                }
            }
        }
#pragma unroll
        for (int j = 0; j < 16; ++j) {
            float sig = __builtin_amdgcn_rcpf(1.f + __expf(-xF[j]));
            float t = __expf(-fabsf(xS[j]));
            float sp = fmaxf(xS[j], 0.f) + __logf(1.f + t);
            agg[j] += sig * sp;
        }
    }

    if (act) {
        float inv = 1.f / (float)max(re - rb, 1);
        size_t base = (size_t)n * 64 + q * 16;
#pragma unroll
        for (int j = 0; j < 16; ++j)
            hout[base + j] = fmaxf(h[base + j] + agg[j] * inv, 0.f);
    }
}

// ---------------------------------------------------------------------------
// Global mean pool
// ---------------------------------------------------------------------------
__global__ __launch_bounds__(256) void pool_kernel(
    const float* __restrict__ h, const int* __restrict__ bm,
    float* __restrict__ gsum, float* __restrict__ cnt, int N)
{
    int idx = blockIdx.x * blockDim.x + threadIdx.x;
    int node = idx >> 6;
    int d = idx & 63;
    if (node >= N) return;
    int b = bm[node];
    atomicAdd(&gsum[(size_t)b * 64 + d], h[idx]);
    if (d == 0) atomicAdd(&cnt[b], 1.f);
}

__global__ __launch_bounds__(256) void pooldiv_kernel(
    float* __restrict__ g, const float* __restrict__ cnt, int B)
{
    int idx = blockIdx.x * blockDim.x + threadIdx.x;
    if (idx >= B * 64) return;
    g[idx] = g[idx] / fmaxf(cnt[idx >> 6], 1.f);
}

__global__ __launch_bounds__(128) void final_kernel(
    const float* __restrict__ g, const float* __restrict__ Wf,
    const float* __restrict__ bf, float* __restrict__ out, int B)
{
    int b = blockIdx.x * blockDim.x + threadIdx.x;
    if (b >= B) return;
    float acc = bf[0];
#pragma unroll
    for (int k = 0; k < 64; ++k)
        acc = fmaf(g[(size_t)b * 64 + k], Wf[k], acc);
    out[b] = acc;
}

extern "C" void kernel_launch(void* const* d_in, const int* in_sizes, int n_in,
                              void* d_out, int out_size, void* d_ws, size_t ws_size,
                              hipStream_t stream)
{
    const float* X      = (const float*)d_in[0];
    const int*   eidx   = (const int*)d_in[1];
    const float* ea     = (const float*)d_in[3];
    const int*   bm     = (const int*)d_in[4];
    const float* pre_W0 = (const float*)d_in[5];
    const float* pre_b0 = (const float*)d_in[6];
    const float* pre_W1 = (const float*)d_in[7];
    const float* pre_b1 = (const float*)d_in[8];
    const float* pre_W2 = (const float*)d_in[9];
    const float* pre_b2 = (const float*)d_in[10];
    const float* cg_Wf  = (const float*)d_in[11];
    const float* cg_bf  = (const float*)d_in[12];
    const float* cg_Ws  = (const float*)d_in[13];
    const float* cg_bs  = (const float*)d_in[14];
    const float* post_W0 = (const float*)d_in[15];
    const float* post_b0 = (const float*)d_in[16];
    const float* post_W1 = (const float*)d_in[17];
    const float* post_b1 = (const float*)d_in[18];
    const float* post_W2 = (const float*)d_in[19];
    const float* post_b2 = (const float*)d_in[20];
    const float* post_Wf = (const float*)d_in[21];
    const float* post_bf = (const float*)d_in[22];

    const int* src = eidx;
    const int* dst = eidx + GE;

    // ---- workspace carve-up ----
    const size_t N64 = (size_t)GN * 64;
    float* hA   = (float*)d_ws;          // N*64
    float* hB   = hA + N64;              // N*64
    int* deg_i  = (int*)(hB + N64);      // N
    int* iscan  = deg_i + GN;            // N
    int* bsum   = iscan + GN;            // 128
    int* boff   = bsum + 128;            // 128
    int* rowptr = boff + 128;            // N+1
    int* cursor = rowptr + GN + 1;       // N
    int* bcnt   = cursor + GN;           // 64
    int* bcur   = bcnt + 64;             // 64
    int* norder = bcur + 64;             // N
    int* e_src  = norder + GN;           // E
    float* e_ea = (float*)(e_src + GE);  // E
    float* g0   = e_ea + GE;             // B*64
    float* g1   = g0 + GB * 64;          // B*64
    float* cnt  = g1 + GB * 64;          // B

    const int TPB = 256;
    int gridE  = (GE + TPB - 1) / TPB;
    int gridN  = (GN + TPB - 1) / TPB;
    int gridBD = (GB * 64 + TPB - 1) / TPB;
    int nodeBlocks = (GN + TPB - 1) / TPB;   // 391
    int scanBlocks = (GN + 1023) / 1024;     // 98

    // pre-GC MLP: X(F)->hA, hA->hB, hB->hA
    mlp64_kernel<<<GN, 64, 0, stream>>>(X,  pre_W0, pre_b0, hA, GF);
    mlp64_kernel<<<GN, 64, 0, stream>>>(hA, pre_W1, pre_b1, hB, GD);
    mlp64_kernel<<<GN, 64, 0, stream>>>(hB, pre_W2, pre_b2, hA, GD);

    // degree + CSR build
    hipMemsetAsync(deg_i, 0, GN * sizeof(int), stream);
    deg_kernel<<<gridE, TPB, 0, stream>>>(dst, deg_i, GE);
    scanA_kernel<<<scanBlocks, 1024, 0, stream>>>(deg_i, iscan, bsum, GN);
    scanB_kernel<<<1, 128, 0, stream>>>(bsum, boff, scanBlocks);
    scanC_kernel<<<gridN, TPB, 0, stream>>>(iscan, boff, deg_i, rowptr, cursor, GN);

    // degree-bucket node ordering
    hipMemsetAsync(bcnt, 0, 64 * sizeof(int), stream);
    bhist_kernel<<<gridN, TPB, 0, stream>>>(deg_i, bcnt, GN);
    bscan_kernel<<<1, 64, 0, stream>>>(bcnt, bcur);
    bscatter_kernel<<<gridN, TPB, 0, stream>>>(deg_i, bcur, norder, GN);

    // edge scatter into CSR order
    escatter_kernel<<<gridE, TPB, 0, stream>>>(src, dst, ea, cursor, e_src, e_ea, GE);

    // CGConv layers (ping-pong hA <-> hB)
    float* hin = hA; float* hout = hB;
    for (int l = 0; l < GL; ++l) {
        gate_pull_kernel<<<nodeBlocks * 4, TPB, 0, stream>>>(
            hin, rowptr, e_src, e_ea, norder,
            cg_Wf + (size_t)l * GZ * GD, cg_bf + (size_t)l * GD,
            cg_Ws + (size_t)l * GZ * GD, cg_bs + (size_t)l * GD,
            hout);
        float* t = hin; hin = hout; hout = t;
    }
    // after 3 layers result is in hin

    // global mean pool
    hipMemsetAsync(g0, 0, GB * 64 * sizeof(float), stream);
    hipMemsetAsync(cnt, 0, GB * sizeof(float), stream);
    pool_kernel<<<(GN * 64 + TPB - 1) / TPB, TPB, 0, stream>>>(hin, bm, g0, cnt, GN);
    pooldiv_kernel<<<gridBD, TPB, 0, stream>>>(g0, cnt, GB);

    // post-GC MLP
    mlp64_kernel<<<GB, 64, 0, stream>>>(g0, post_W0, post_b0, g1, GD);
    mlp64_kernel<<<GB, 64, 0, stream>>>(g1, post_W1, post_b1, g0, GD);
    mlp64_kernel<<<GB, 64, 0, stream>>>(g0, post_W2, post_b2, g1, GD);
    final_kernel<<<1, 128, 0, stream>>>(g1, post_Wf, post_bf, (float*)d_out, GB);
}

// Round 3
// 2923.617 us; speedup vs baseline: 4.6097x; 1.1969x over previous
//
#include <hip/hip_runtime.h>
#include <hip/hip_bf16.h>
#include <math.h>

// Problem constants (fixed by the reference)
#define GN 100000   // nodes
#define GE 1200000  // edges
#define GB 128      // graphs
#define GF 92       // raw features
#define GD 64       // hidden dim
#define GL 3        // CGConv layers
#define GZ 129      // 2*D+1

// ---------------------------------------------------------------------------
// Dense layer, one node per 64-thread block: out[n,d] = relu(in[n,:K]@W[:,d]+b[d])
// blockIdx-derived row pointer -> provably wave-uniform -> s_load stream;
// W[k*64+d] coalesced across lanes.
// ---------------------------------------------------------------------------
__global__ __launch_bounds__(64) void mlp64_kernel(
    const float* __restrict__ in, const float* __restrict__ W,
    const float* __restrict__ b, float* __restrict__ out, int K)
{
    int n = blockIdx.x;
    int d = threadIdx.x;
    const float* __restrict__ row = in + (size_t)n * K;
    float acc = b[d];
    for (int k = 0; k < K; ++k)
        acc = fmaf(row[k], W[k * 64 + d], acc);
    out[(size_t)n * 64 + d] = fmaxf(acc, 0.f);
}

// ---------------------------------------------------------------------------
// In-degree histogram (int)
// ---------------------------------------------------------------------------
__global__ __launch_bounds__(256) void deg_kernel(
    const int* __restrict__ dst, int* __restrict__ deg, int E)
{
    int e = blockIdx.x * blockDim.x + threadIdx.x;
    if (e < E) atomicAdd(&deg[dst[e]], 1);
}

// ---------------------------------------------------------------------------
// Three-phase exclusive scan over deg -> rowptr, cursor
// ---------------------------------------------------------------------------
__global__ __launch_bounds__(1024) void scanA_kernel(
    const int* __restrict__ deg, int* __restrict__ iscan,
    int* __restrict__ bsum, int N)
{
    __shared__ int lds[1024];
    int tid = threadIdx.x;
    int gid = blockIdx.x * 1024 + tid;
    int v = (gid < N) ? deg[gid] : 0;
    lds[tid] = v; __syncthreads();
    for (int off = 1; off < 1024; off <<= 1) {
        int t = (tid >= off) ? lds[tid - off] : 0;
        __syncthreads();
        lds[tid] += t;
        __syncthreads();
    }
    if (gid < N) iscan[gid] = lds[tid];
    if (tid == 1023) bsum[blockIdx.x] = lds[1023];
}

__global__ __launch_bounds__(128) void scanB_kernel(
    const int* __restrict__ bsum, int* __restrict__ boff, int nb)
{
    __shared__ int lds[128];
    int t = threadIdx.x;
    int v = (t < nb) ? bsum[t] : 0;
    lds[t] = v; __syncthreads();
    for (int off = 1; off < 128; off <<= 1) {
        int u = (t >= off) ? lds[t - off] : 0;
        __syncthreads();
        lds[t] += u;
        __syncthreads();
    }
    if (t < nb) boff[t] = lds[t] - v;  // exclusive
}

__global__ __launch_bounds__(256) void scanC_kernel(
    const int* __restrict__ iscan, const int* __restrict__ boff,
    const int* __restrict__ deg,
    int* __restrict__ rowptr, int* __restrict__ cursor, int N)
{
    int i = blockIdx.x * blockDim.x + threadIdx.x;
    if (i >= N) return;
    int incl = iscan[i] + boff[i >> 10];
    rowptr[i + 1] = incl;
    cursor[i] = incl - deg[i];
    if (i == 0) rowptr[0] = 0;
}

// ---------------------------------------------------------------------------
// Degree-bucket ordering (equal-degree nodes adjacent -> no wave divergence)
// ---------------------------------------------------------------------------
__global__ __launch_bounds__(256) void bhist_kernel(
    const int* __restrict__ deg, int* __restrict__ bcnt, int N)
{
    int n = blockIdx.x * blockDim.x + threadIdx.x;
    if (n < N) atomicAdd(&bcnt[min(deg[n], 63)], 1);
}

__global__ __launch_bounds__(64) void bscan_kernel(
    const int* __restrict__ bcnt, int* __restrict__ bcur)
{
    __shared__ int lds[64];
    int t = threadIdx.x;
    int v = bcnt[t];
    lds[t] = v; __syncthreads();
    for (int off = 1; off < 64; off <<= 1) {
        int u = (t >= off) ? lds[t - off] : 0;
        __syncthreads();
        lds[t] += u;
        __syncthreads();
    }
    bcur[t] = lds[t] - v;  // exclusive start
}

__global__ __launch_bounds__(256) void bscatter_kernel(
    const int* __restrict__ deg, int* __restrict__ bcur,
    int* __restrict__ node_order, int N)
{
    int n = blockIdx.x * blockDim.x + threadIdx.x;
    if (n >= N) return;
    int pos = atomicAdd(&bcur[min(deg[n], 63)], 1);
    node_order[pos] = n;
}

// ---------------------------------------------------------------------------
// Edge scatter into CSR order: e_src/e_ea sorted by dst
// ---------------------------------------------------------------------------
__global__ __launch_bounds__(256) void escatter_kernel(
    const int* __restrict__ src, const int* __restrict__ dst,
    const float* __restrict__ ea, int* __restrict__ cursor,
    int* __restrict__ e_src, float* __restrict__ e_ea, int E)
{
    int e = blockIdx.x * blockDim.x + threadIdx.x;
    if (e >= E) return;
    int pos = atomicAdd(&cursor[dst[e]], 1);
    e_src[pos] = src[e];
    e_ea[pos] = ea[e];
}

// ---------------------------------------------------------------------------
// CGConv, pull form. Thread = (node, 16-wide output quarter).
// quarter = blockIdx&3 (block-uniform -> weight loads are s_load streams,
// shared by all 64 lanes in lockstep over their edge lists).
// Per node: base = bias + h[dst]@W[0:64] computed once; per edge only the
// h[src]@W[64:128] + ea*W[128] part. Residual+relu+mean fused at the end.
// ---------------------------------------------------------------------------
__global__ __launch_bounds__(256) void gate_pull_kernel(
    const float* __restrict__ h, const int* __restrict__ rowptr,
    const int* __restrict__ e_src, const float* __restrict__ e_ea,
    const int* __restrict__ node_order,
    const float* __restrict__ Wf, const float* __restrict__ bfv,
    const float* __restrict__ Ws, const float* __restrict__ bsv,
    float* __restrict__ hout)
{
    const int q = blockIdx.x & 3;   // block-uniform output quarter
    int slot = (blockIdx.x >> 2) * 256 + threadIdx.x;
    bool act = slot < GN;
    int n = act ? node_order[slot] : 0;
    int rb = rowptr[n];
    int re = act ? rowptr[n + 1] : rb;

    const float* __restrict__ Wfq = Wf + q * 16;
    const float* __restrict__ Wsq = Ws + q * 16;

    // base: bias + h[dst] part (once per node)
    float bF[16], bS[16];
#pragma unroll
    for (int j = 0; j < 16; ++j) { bF[j] = bfv[q * 16 + j]; bS[j] = bsv[q * 16 + j]; }
    const float4* __restrict__ hd4 = (const float4*)(h + (size_t)n * 64);
#pragma unroll 4
    for (int c = 0; c < 16; ++c) {
        float4 v = hd4[c];
#pragma unroll
        for (int i = 0; i < 4; ++i) {
            float zk = (i == 0) ? v.x : (i == 1) ? v.y : (i == 2) ? v.z : v.w;
            const float* __restrict__ w1 = Wfq + (c * 4 + i) * 64;
            const float* __restrict__ w2 = Wsq + (c * 4 + i) * 64;
#pragma unroll
            for (int j = 0; j < 16; ++j) {
                bF[j] = fmaf(zk, w1[j], bF[j]);
                bS[j] = fmaf(zk, w2[j], bS[j]);
            }
        }
    }

    float agg[16];
#pragma unroll
    for (int j = 0; j < 16; ++j) agg[j] = 0.f;

    for (int p = rb; p < re; ++p) {
        int s = e_src[p];
        float eav = e_ea[p];
        const float4* __restrict__ hs4 = (const float4*)(h + (size_t)s * 64);
        float xF[16], xS[16];
#pragma unroll
        for (int j = 0; j < 16; ++j) {
            xF[j] = fmaf(eav, Wfq[128 * 64 + j], bF[j]);
            xS[j] = fmaf(eav, Wsq[128 * 64 + j], bS[j]);
        }
#pragma unroll 4
        for (int c = 0; c < 16; ++c) {
            float4 v = hs4[c];
#pragma unroll
            for (int i = 0; i < 4; ++i) {
                float zk = (i == 0) ? v.x : (i == 1) ? v.y : (i == 2) ? v.z : v.w;
                const float* __restrict__ w1 = Wfq + (64 + c * 4 + i) * 64;
                const float* __restrict__ w2 = Wsq + (64 + c * 4 + i) * 64;
#pragma unroll
                for (int j = 0; j < 16; ++j) {
                    xF[j] = fmaf(zk, w1[j], xF[j]);
                    xS[j] = fmaf(zk, w2[j], xS[j]);
                }
            }
        }
#pragma unroll
        for (int j = 0; j < 16; ++j) {
            float sig = __builtin_amdgcn_rcpf(1.f + __expf(-xF[j]));
            float t = __expf(-fabsf(xS[j]));
            float sp = fmaxf(xS[j], 0.f) + __logf(1.f + t);
            agg[j] += sig * sp;
        }
    }

    if (act) {
        float inv = 1.f / (float)max(re - rb, 1);
        size_t base = (size_t)n * 64 + q * 16;
#pragma unroll
        for (int j = 0; j < 16; ++j)
            hout[base + j] = fmaxf(h[base + j] + agg[j] * inv, 0.f);
    }
}

// ---------------------------------------------------------------------------
// Graph segment starts: bm is sorted; gstart[b] = first node index of graph b.
// gstart[GB] = N. Empty graphs get start == next start (count 0).
// ---------------------------------------------------------------------------
__global__ __launch_bounds__(256) void gstart_kernel(
    const int* __restrict__ bm, int* __restrict__ gstart, int N)
{
    int i = blockIdx.x * blockDim.x + threadIdx.x;
    if (i >= N) return;
    int b = bm[i];
    int prev = (i == 0) ? -1 : bm[i - 1];
    for (int g = prev + 1; g <= b; ++g) gstart[g] = i;
    if (i == N - 1)
        for (int g = b + 1; g <= GB; ++g) gstart[g] = N;
}

// ---------------------------------------------------------------------------
// Segmented mean pool: one block per graph, no atomics.
// 4 waves stride the node range (coalesced 256B row reads), LDS-reduce,
// mean-divide fused.
// ---------------------------------------------------------------------------
__global__ __launch_bounds__(256) void pool_seg_kernel(
    const float* __restrict__ h, const int* __restrict__ gstart,
    float* __restrict__ g)
{
    int b = blockIdx.x;
    int s = gstart[b], e = gstart[b + 1];
    int d = threadIdx.x & 63;
    int w = threadIdx.x >> 6;   // wave 0..3
    float acc = 0.f;
    for (int n = s + w; n < e; n += 4)
        acc += h[(size_t)n * 64 + d];
    __shared__ float lds[256];
    lds[threadIdx.x] = acc;
    __syncthreads();
    if (w == 0) {
        acc = lds[d] + lds[64 + d] + lds[128 + d] + lds[192 + d];
        g[b * 64 + d] = acc / fmaxf((float)(e - s), 1.f);
    }
}

__global__ __launch_bounds__(128) void final_kernel(
    const float* __restrict__ g, const float* __restrict__ Wf,
    const float* __restrict__ bf, float* __restrict__ out, int B)
{
    int b = blockIdx.x * blockDim.x + threadIdx.x;
    if (b >= B) return;
    float acc = bf[0];
#pragma unroll
    for (int k = 0; k < 64; ++k)
        acc = fmaf(g[(size_t)b * 64 + k], Wf[k], acc);
    out[b] = acc;
}

extern "C" void kernel_launch(void* const* d_in, const int* in_sizes, int n_in,
                              void* d_out, int out_size, void* d_ws, size_t ws_size,
                              hipStream_t stream)
{
    const float* X      = (const float*)d_in[0];
    const int*   eidx   = (const int*)d_in[1];
    const float* ea     = (const float*)d_in[3];
    const int*   bm     = (const int*)d_in[4];
    const float* pre_W0 = (const float*)d_in[5];
    const float* pre_b0 = (const float*)d_in[6];
    const float* pre_W1 = (const float*)d_in[7];
    const float* pre_b1 = (const float*)d_in[8];
    const float* pre_W2 = (const float*)d_in[9];
    const float* pre_b2 = (const float*)d_in[10];
    const float* cg_Wf  = (const float*)d_in[11];
    const float* cg_bf  = (const float*)d_in[12];
    const float* cg_Ws  = (const float*)d_in[13];
    const float* cg_bs  = (const float*)d_in[14];
    const float* post_W0 = (const float*)d_in[15];
    const float* post_b0 = (const float*)d_in[16];
    const float* post_W1 = (const float*)d_in[17];
    const float* post_b1 = (const float*)d_in[18];
    const float* post_W2 = (const float*)d_in[19];
    const float* post_b2 = (const float*)d_in[20];
    const float* post_Wf = (const float*)d_in[21];
    const float* post_bf = (const float*)d_in[22];

    const int* src = eidx;
    const int* dst = eidx + GE;

    // ---- workspace carve-up ----
    const size_t N64 = (size_t)GN * 64;
    float* hA    = (float*)d_ws;          // N*64
    float* hB    = hA + N64;              // N*64
    int* deg_i   = (int*)(hB + N64);      // N
    int* iscan   = deg_i + GN;            // N
    int* bsum    = iscan + GN;            // 128
    int* boff    = bsum + 128;            // 128
    int* rowptr  = boff + 128;            // N+1
    int* cursor  = rowptr + GN + 1;       // N
    int* bcnt    = cursor + GN;           // 64
    int* bcur    = bcnt + 64;             // 64
    int* norder  = bcur + 64;             // N
    int* e_src   = norder + GN;           // E
    float* e_ea  = (float*)(e_src + GE);  // E
    int* gstart  = (int*)(e_ea + GE);     // B+1
    float* g0    = (float*)(gstart + GB + 1); // B*64
    float* g1    = g0 + GB * 64;          // B*64

    const int TPB = 256;
    int gridE  = (GE + TPB - 1) / TPB;
    int gridN  = (GN + TPB - 1) / TPB;
    int nodeBlocks = (GN + TPB - 1) / TPB;   // 391
    int scanBlocks = (GN + 1023) / 1024;     // 98

    // pre-GC MLP: X(F)->hA, hA->hB, hB->hA
    mlp64_kernel<<<GN, 64, 0, stream>>>(X,  pre_W0, pre_b0, hA, GF);
    mlp64_kernel<<<GN, 64, 0, stream>>>(hA, pre_W1, pre_b1, hB, GD);
    mlp64_kernel<<<GN, 64, 0, stream>>>(hB, pre_W2, pre_b2, hA, GD);

    // degree + CSR build
    hipMemsetAsync(deg_i, 0, GN * sizeof(int), stream);
    deg_kernel<<<gridE, TPB, 0, stream>>>(dst, deg_i, GE);
    scanA_kernel<<<scanBlocks, 1024, 0, stream>>>(deg_i, iscan, bsum, GN);
    scanB_kernel<<<1, 128, 0, stream>>>(bsum, boff, scanBlocks);
    scanC_kernel<<<gridN, TPB, 0, stream>>>(iscan, boff, deg_i, rowptr, cursor, GN);

    // degree-bucket node ordering
    hipMemsetAsync(bcnt, 0, 64 * sizeof(int), stream);
    bhist_kernel<<<gridN, TPB, 0, stream>>>(deg_i, bcnt, GN);
    bscan_kernel<<<1, 64, 0, stream>>>(bcnt, bcur);
    bscatter_kernel<<<gridN, TPB, 0, stream>>>(deg_i, bcur, norder, GN);

    // edge scatter into CSR order
    escatter_kernel<<<gridE, TPB, 0, stream>>>(src, dst, ea, cursor, e_src, e_ea, GE);

    // graph segment starts (bm sorted)
    gstart_kernel<<<gridN, TPB, 0, stream>>>(bm, gstart, GN);

    // CGConv layers (ping-pong hA <-> hB)
    float* hin = hA; float* hout = hB;
    for (int l = 0; l < GL; ++l) {
        gate_pull_kernel<<<nodeBlocks * 4, TPB, 0, stream>>>(
            hin, rowptr, e_src, e_ea, norder,
            cg_Wf + (size_t)l * GZ * GD, cg_bf + (size_t)l * GD,
            cg_Ws + (size_t)l * GZ * GD, cg_bs + (size_t)l * GD,
            hout);
        float* t = hin; hin = hout; hout = t;
    }
    // after 3 layers result is in hin

    // segmented mean pool (no atomics)
    pool_seg_kernel<<<GB, TPB, 0, stream>>>(hin, gstart, g0);

    // post-GC MLP
    mlp64_kernel<<<GB, 64, 0, stream>>>(g0, post_W0, post_b0, g1, GD);
    mlp64_kernel<<<GB, 64, 0, stream>>>(g1, post_W1, post_b1, g0, GD);
    mlp64_kernel<<<GB, 64, 0, stream>>>(g0, post_W2, post_b2, g1, GD);
    final_kernel<<<1, 128, 0, stream>>>(g1, post_Wf, post_bf, (float*)d_out, GB);
}

// Round 4
// 1997.874 us; speedup vs baseline: 6.7456x; 1.4634x over previous
//
#include <hip/hip_runtime.h>
#include <hip/hip_bf16.h>
#include <math.h>

// Problem constants (fixed by the reference)
#define GN 100000   // nodes
#define GE 1200000  // edges
#define GB 128      // graphs
#define GF 92       // raw features
#define GD 64       // hidden dim
#define GL 3        // CGConv layers
#define GZ 129      // 2*D+1

// ---------------------------------------------------------------------------
// Dense layer: thread=(node,d). Row reads wave-uniform (scalar stream),
// W reads coalesced + cached. out = relu(in@W + b)
// ---------------------------------------------------------------------------
__global__ __launch_bounds__(256) void mlp_kernel(
    const float* __restrict__ in, const float* __restrict__ W,
    const float* __restrict__ b, float* __restrict__ out,
    int N, int K)
{
    int t = blockIdx.x * 256 + threadIdx.x;
    int n = t >> 6;
    int d = t & 63;
    if (n >= N) return;
    const float* __restrict__ row = in + (size_t)n * K;
    float acc = b[d];
    for (int k = 0; k < K; ++k)
        acc = fmaf(row[k], W[k * 64 + d], acc);
    out[(size_t)n * 64 + d] = fmaxf(acc, 0.f);
}

// ---------------------------------------------------------------------------
// In-degree histogram (int)
// ---------------------------------------------------------------------------
__global__ __launch_bounds__(256) void deg_kernel(
    const int* __restrict__ dst, int* __restrict__ deg, int E)
{
    int e = blockIdx.x * blockDim.x + threadIdx.x;
    if (e < E) atomicAdd(&deg[dst[e]], 1);
}

// ---------------------------------------------------------------------------
// Three-phase exclusive scan over deg -> rowptr, cursor
// ---------------------------------------------------------------------------
__global__ __launch_bounds__(1024) void scanA_kernel(
    const int* __restrict__ deg, int* __restrict__ iscan,
    int* __restrict__ bsum, int N)
{
    __shared__ int lds[1024];
    int tid = threadIdx.x;
    int gid = blockIdx.x * 1024 + tid;
    int v = (gid < N) ? deg[gid] : 0;
    lds[tid] = v; __syncthreads();
    for (int off = 1; off < 1024; off <<= 1) {
        int t = (tid >= off) ? lds[tid - off] : 0;
        __syncthreads();
        lds[tid] += t;
        __syncthreads();
    }
    if (gid < N) iscan[gid] = lds[tid];
    if (tid == 1023) bsum[blockIdx.x] = lds[1023];
}

__global__ __launch_bounds__(128) void scanB_kernel(
    const int* __restrict__ bsum, int* __restrict__ boff, int nb)
{
    __shared__ int lds[128];
    int t = threadIdx.x;
    int v = (t < nb) ? bsum[t] : 0;
    lds[t] = v; __syncthreads();
    for (int off = 1; off < 128; off <<= 1) {
        int u = (t >= off) ? lds[t - off] : 0;
        __syncthreads();
        lds[t] += u;
        __syncthreads();
    }
    if (t < nb) boff[t] = lds[t] - v;  // exclusive
}

__global__ __launch_bounds__(256) void scanC_kernel(
    const int* __restrict__ iscan, const int* __restrict__ boff,
    const int* __restrict__ deg,
    int* __restrict__ rowptr, int* __restrict__ cursor, int N)
{
    int i = blockIdx.x * blockDim.x + threadIdx.x;
    if (i >= N) return;
    int incl = iscan[i] + boff[i >> 10];
    rowptr[i + 1] = incl;
    cursor[i] = incl - deg[i];
    if (i == 0) rowptr[0] = 0;
}

// ---------------------------------------------------------------------------
// Edge scatter into CSR order: e_src/e_ea sorted by dst
// ---------------------------------------------------------------------------
__global__ __launch_bounds__(256) void escatter_kernel(
    const int* __restrict__ src, const int* __restrict__ dst,
    const float* __restrict__ ea, int* __restrict__ cursor,
    int* __restrict__ e_src, float* __restrict__ e_ea, int E)
{
    int e = blockIdx.x * blockDim.x + threadIdx.x;
    if (e >= E) return;
    int pos = atomicAdd(&cursor[dst[e]], 1);
    e_src[pos] = src[e];
    e_ea[pos] = ea[e];
}

// ---------------------------------------------------------------------------
// Per-layer src-projection: P[n] = { h[n]@Wf[64:128] , h[n]@Ws[64:128] }
// interleaved as float2 per dim -> edge gather is one dwordx2 per lane.
// thread=(node,d); h row reads wave-uniform, weight streams L1/L2-cached.
// ---------------------------------------------------------------------------
__global__ __launch_bounds__(256) void proj_kernel(
    const float* __restrict__ h,
    const float* __restrict__ Wf, const float* __restrict__ Ws,
    float2* __restrict__ P)
{
    int t = blockIdx.x * 256 + threadIdx.x;
    int n = t >> 6;
    int d = t & 63;
    if (n >= GN) return;
    const float* __restrict__ row = h + (size_t)n * 64;
    const float* __restrict__ WfP = Wf + 64 * 64;   // rows 64..127
    const float* __restrict__ WsP = Ws + 64 * 64;
    float pf = 0.f, ps = 0.f;
#pragma unroll 8
    for (int k = 0; k < 64; ++k) {
        float hk = row[k];
        pf = fmaf(hk, WfP[k * 64 + d], pf);
        ps = fmaf(hk, WsP[k * 64 + d], ps);
    }
    P[(size_t)n * 64 + d] = make_float2(pf, ps);
}

// ---------------------------------------------------------------------------
// CGConv edge pass, linearized. One 64-lane wave per node, lane = dim.
//   base (inline): q = bias + h[n]@W[0:64]   (both gates)
//   per edge:      x = q + P[src] + ea*W[128];  agg += sigmoid(xF)*softplus(xS)
//   epilogue:      hout = relu(h + agg/deg)
// e_src/e_ea reads are wave-uniform (one line, broadcast). P gather is the
// only random traffic: 512 B/edge (the minimum at fp32).
// ---------------------------------------------------------------------------
__global__ __launch_bounds__(256) void edge_kernel(
    const float* __restrict__ h, const int* __restrict__ rowptr,
    const int* __restrict__ e_src, const float* __restrict__ e_ea,
    const float2* __restrict__ P,
    const float* __restrict__ Wf, const float* __restrict__ bfv,
    const float* __restrict__ Ws, const float* __restrict__ bsv,
    float* __restrict__ hout)
{
    int n = blockIdx.x * 4 + (threadIdx.x >> 6);
    int d = threadIdx.x & 63;
    if (n >= GN) return;

    // inline dst-projection (weight streams are cache-resident)
    const float* __restrict__ row = h + (size_t)n * 64;
    float qf = bfv[d], qs = bsv[d];
#pragma unroll 8
    for (int k = 0; k < 64; ++k) {
        float hk = row[k];
        qf = fmaf(hk, Wf[k * 64 + d], qf);
        qs = fmaf(hk, Ws[k * 64 + d], qs);
    }
    float wf = Wf[128 * 64 + d];
    float ws = Ws[128 * 64 + d];

    int rb = rowptr[n], re = rowptr[n + 1];
    float agg = 0.f;
    for (int p = rb; p < re; ++p) {
        int s = e_src[p];          // wave-uniform
        float ea = e_ea[p];        // wave-uniform
        float2 pv = P[(size_t)s * 64 + d];   // gathered, coalesced in d
        float xF = fmaf(ea, wf, qf + pv.x);
        float xS = fmaf(ea, ws, qs + pv.y);
        float sig = __builtin_amdgcn_rcpf(1.f + __expf(-xF));
        float t = __expf(-fabsf(xS));
        float sp = fmaxf(xS, 0.f) + __logf(1.f + t);
        agg = fmaf(sig, sp, agg);
    }

    float inv = 1.f / (float)max(re - rb, 1);
    size_t idx = (size_t)n * 64 + d;
    hout[idx] = fmaxf(h[idx] + agg * inv, 0.f);
}

// ---------------------------------------------------------------------------
// Graph segment starts: bm sorted; gstart[b] = first node of graph b.
// ---------------------------------------------------------------------------
__global__ __launch_bounds__(256) void gstart_kernel(
    const int* __restrict__ bm, int* __restrict__ gstart, int N)
{
    int i = blockIdx.x * blockDim.x + threadIdx.x;
    if (i >= N) return;
    int b = bm[i];
    int prev = (i == 0) ? -1 : bm[i - 1];
    for (int g = prev + 1; g <= b; ++g) gstart[g] = i;
    if (i == N - 1)
        for (int g = b + 1; g <= GB; ++g) gstart[g] = N;
}

// ---------------------------------------------------------------------------
// Segmented mean pool: one block per graph, no atomics.
// ---------------------------------------------------------------------------
__global__ __launch_bounds__(256) void pool_seg_kernel(
    const float* __restrict__ h, const int* __restrict__ gstart,
    float* __restrict__ g)
{
    int b = blockIdx.x;
    int s = gstart[b], e = gstart[b + 1];
    int d = threadIdx.x & 63;
    int w = threadIdx.x >> 6;
    float acc = 0.f;
    for (int n = s + w; n < e; n += 4)
        acc += h[(size_t)n * 64 + d];
    __shared__ float lds[256];
    lds[threadIdx.x] = acc;
    __syncthreads();
    if (w == 0) {
        acc = lds[d] + lds[64 + d] + lds[128 + d] + lds[192 + d];
        g[b * 64 + d] = acc / fmaxf((float)(e - s), 1.f);
    }
}

__global__ __launch_bounds__(128) void final_kernel(
    const float* __restrict__ g, const float* __restrict__ Wf,
    const float* __restrict__ bf, float* __restrict__ out, int B)
{
    int b = blockIdx.x * blockDim.x + threadIdx.x;
    if (b >= B) return;
    float acc = bf[0];
#pragma unroll
    for (int k = 0; k < 64; ++k)
        acc = fmaf(g[(size_t)b * 64 + k], Wf[k], acc);
    out[b] = acc;
}

extern "C" void kernel_launch(void* const* d_in, const int* in_sizes, int n_in,
                              void* d_out, int out_size, void* d_ws, size_t ws_size,
                              hipStream_t stream)
{
    const float* X      = (const float*)d_in[0];
    const int*   eidx   = (const int*)d_in[1];
    const float* ea     = (const float*)d_in[3];
    const int*   bm     = (const int*)d_in[4];
    const float* pre_W0 = (const float*)d_in[5];
    const float* pre_b0 = (const float*)d_in[6];
    const float* pre_W1 = (const float*)d_in[7];
    const float* pre_b1 = (const float*)d_in[8];
    const float* pre_W2 = (const float*)d_in[9];
    const float* pre_b2 = (const float*)d_in[10];
    const float* cg_Wf  = (const float*)d_in[11];
    const float* cg_bf  = (const float*)d_in[12];
    const float* cg_Ws  = (const float*)d_in[13];
    const float* cg_bs  = (const float*)d_in[14];
    const float* post_W0 = (const float*)d_in[15];
    const float* post_b0 = (const float*)d_in[16];
    const float* post_W1 = (const float*)d_in[17];
    const float* post_b1 = (const float*)d_in[18];
    const float* post_W2 = (const float*)d_in[19];
    const float* post_b2 = (const float*)d_in[20];
    const float* post_Wf = (const float*)d_in[21];
    const float* post_bf = (const float*)d_in[22];

    const int* src = eidx;
    const int* dst = eidx + GE;

    // ---- workspace carve-up ----
    const size_t N64 = (size_t)GN * 64;
    float* hA    = (float*)d_ws;          // N*64
    float* hB    = hA + N64;              // N*64
    float2* P    = (float2*)(hB + N64);   // N*64 float2 (= N*128 floats)
    int* deg_i   = (int*)(P + N64);       // N
    int* iscan   = deg_i + GN;            // N
    int* bsum    = iscan + GN;            // 128
    int* boff    = bsum + 128;            // 128
    int* rowptr  = boff + 128;            // N+1
    int* cursor  = rowptr + GN + 1;       // N
    int* e_src   = cursor + GN;           // E
    float* e_ea  = (float*)(e_src + GE);  // E
    int* gstart  = (int*)(e_ea + GE);     // B+1
    float* g0    = (float*)(gstart + GB + 1); // B*64
    float* g1    = g0 + GB * 64;          // B*64

    const int TPB = 256;
    int gridE  = (GE + TPB - 1) / TPB;
    int gridN  = (GN + TPB - 1) / TPB;
    int gridND = ((GN * 64) + TPB - 1) / TPB;  // 25000
    int scanBlocks = (GN + 1023) / 1024;       // 98

    // pre-GC MLP: X(F)->hA, hA->hB, hB->hA
    mlp_kernel<<<gridND, TPB, 0, stream>>>(X,  pre_W0, pre_b0, hA, GN, GF);
    mlp_kernel<<<gridND, TPB, 0, stream>>>(hA, pre_W1, pre_b1, hB, GN, GD);
    mlp_kernel<<<gridND, TPB, 0, stream>>>(hB, pre_W2, pre_b2, hA, GN, GD);

    // degree + CSR build
    hipMemsetAsync(deg_i, 0, GN * sizeof(int), stream);
    deg_kernel<<<gridE, TPB, 0, stream>>>(dst, deg_i, GE);
    scanA_kernel<<<scanBlocks, 1024, 0, stream>>>(deg_i, iscan, bsum, GN);
    scanB_kernel<<<1, 128, 0, stream>>>(bsum, boff, scanBlocks);
    scanC_kernel<<<gridN, TPB, 0, stream>>>(iscan, boff, deg_i, rowptr, cursor, GN);
    escatter_kernel<<<gridE, TPB, 0, stream>>>(src, dst, ea, cursor, e_src, e_ea, GE);

    // graph segment starts (bm sorted)
    gstart_kernel<<<gridN, TPB, 0, stream>>>(bm, gstart, GN);

    // CGConv layers (ping-pong hA <-> hB)
    float* hin = hA; float* hout = hB;
    for (int l = 0; l < GL; ++l) {
        const float* Wf = cg_Wf + (size_t)l * GZ * GD;
        const float* Ws = cg_Ws + (size_t)l * GZ * GD;
        proj_kernel<<<gridND, TPB, 0, stream>>>(hin, Wf, Ws, P);
        edge_kernel<<<gridND, TPB, 0, stream>>>(
            hin, rowptr, e_src, e_ea, P,
            Wf, cg_bf + (size_t)l * GD,
            Ws, cg_bs + (size_t)l * GD,
            hout);
        float* t = hin; hin = hout; hout = t;
    }
    // after 3 layers result is in hin

    // segmented mean pool (no atomics)
    pool_seg_kernel<<<GB, TPB, 0, stream>>>(hin, gstart, g0);

    // post-GC MLP
    mlp_kernel<<<(GB * 64 + TPB - 1) / TPB, TPB, 0, stream>>>(g0, post_W0, post_b0, g1, GB, GD);
    mlp_kernel<<<(GB * 64 + TPB - 1) / TPB, TPB, 0, stream>>>(g1, post_W1, post_b1, g0, GB, GD);
    mlp_kernel<<<(GB * 64 + TPB - 1) / TPB, TPB, 0, stream>>>(g0, post_W2, post_b2, g1, GB, GD);
    final_kernel<<<1, 128, 0, stream>>>(g1, post_Wf, post_bf, (float*)d_out, GB);
}

// Round 5
// 1625.608 us; speedup vs baseline: 8.2904x; 1.2290x over previous
//
#include <hip/hip_runtime.h>
#include <hip/hip_bf16.h>
#include <math.h>

// Problem constants (fixed by the reference)
#define GN 100000   // nodes
#define GE 1200000  // edges
#define GB 128      // graphs
#define GF 92       // raw features
#define GD 64       // hidden dim
#define GL 3        // CGConv layers
#define GZ 129      // 2*D+1

// ---------------------------------------------------------------------------
// Dense layer, K=92 (X input, rows NOT 16B-aligned -> scalar unrolled
// broadcast loads). thread=(node,d); W reads coalesced, L1-resident.
// ---------------------------------------------------------------------------
__global__ __launch_bounds__(256) void mlp92_kernel(
    const float* __restrict__ in, const float* __restrict__ W,
    const float* __restrict__ b, float* __restrict__ out, int N)
{
    int t = blockIdx.x * 256 + threadIdx.x;
    int n = t >> 6;
    int d = t & 63;
    if (n >= N) return;
    const float* __restrict__ row = in + (size_t)n * GF;
    float acc = b[d];
#pragma unroll
    for (int k = 0; k < GF; ++k)
        acc = fmaf(row[k], W[k * 64 + d], acc);
    out[(size_t)n * 64 + d] = fmaxf(acc, 0.f);
}

// ---------------------------------------------------------------------------
// Dense layer, K=64 (rows 256B-aligned -> float4 loads, full unroll).
// ---------------------------------------------------------------------------
__global__ __launch_bounds__(256) void mlp64_kernel(
    const float* __restrict__ in, const float* __restrict__ W,
    const float* __restrict__ b, float* __restrict__ out, int N)
{
    int t = blockIdx.x * 256 + threadIdx.x;
    int n = t >> 6;
    int d = t & 63;
    if (n >= N) return;
    const float4* __restrict__ row4 = (const float4*)(in + (size_t)n * 64);
    float acc = b[d];
#pragma unroll
    for (int c = 0; c < 16; ++c) {
        float4 v = row4[c];
        acc = fmaf(v.x, W[(c * 4 + 0) * 64 + d], acc);
        acc = fmaf(v.y, W[(c * 4 + 1) * 64 + d], acc);
        acc = fmaf(v.z, W[(c * 4 + 2) * 64 + d], acc);
        acc = fmaf(v.w, W[(c * 4 + 3) * 64 + d], acc);
    }
    out[(size_t)n * 64 + d] = fmaxf(acc, 0.f);
}

// ---------------------------------------------------------------------------
// In-degree histogram (int)
// ---------------------------------------------------------------------------
__global__ __launch_bounds__(256) void deg_kernel(
    const int* __restrict__ dst, int* __restrict__ deg, int E)
{
    int e = blockIdx.x * blockDim.x + threadIdx.x;
    if (e < E) atomicAdd(&deg[dst[e]], 1);
}

// ---------------------------------------------------------------------------
// Three-phase exclusive scan over deg -> rowptr, cursor
// ---------------------------------------------------------------------------
__global__ __launch_bounds__(1024) void scanA_kernel(
    const int* __restrict__ deg, int* __restrict__ iscan,
    int* __restrict__ bsum, int N)
{
    __shared__ int lds[1024];
    int tid = threadIdx.x;
    int gid = blockIdx.x * 1024 + tid;
    int v = (gid < N) ? deg[gid] : 0;
    lds[tid] = v; __syncthreads();
    for (int off = 1; off < 1024; off <<= 1) {
        int t = (tid >= off) ? lds[tid - off] : 0;
        __syncthreads();
        lds[tid] += t;
        __syncthreads();
    }
    if (gid < N) iscan[gid] = lds[tid];
    if (tid == 1023) bsum[blockIdx.x] = lds[1023];
}

__global__ __launch_bounds__(128) void scanB_kernel(
    const int* __restrict__ bsum, int* __restrict__ boff, int nb)
{
    __shared__ int lds[128];
    int t = threadIdx.x;
    int v = (t < nb) ? bsum[t] : 0;
    lds[t] = v; __syncthreads();
    for (int off = 1; off < 128; off <<= 1) {
        int u = (t >= off) ? lds[t - off] : 0;
        __syncthreads();
        lds[t] += u;
        __syncthreads();
    }
    if (t < nb) boff[t] = lds[t] - v;  // exclusive
}

__global__ __launch_bounds__(256) void scanC_kernel(
    const int* __restrict__ iscan, const int* __restrict__ boff,
    const int* __restrict__ deg,
    int* __restrict__ rowptr, int* __restrict__ cursor, int N)
{
    int i = blockIdx.x * blockDim.x + threadIdx.x;
    if (i >= N) return;
    int incl = iscan[i] + boff[i >> 10];
    rowptr[i + 1] = incl;
    cursor[i] = incl - deg[i];
    if (i == 0) rowptr[0] = 0;
}

// ---------------------------------------------------------------------------
// Edge scatter into CSR order, packed (src, ea) int2
// ---------------------------------------------------------------------------
__global__ __launch_bounds__(256) void escatter_kernel(
    const int* __restrict__ src, const int* __restrict__ dst,
    const float* __restrict__ ea, int* __restrict__ cursor,
    int2* __restrict__ e_se, int E)
{
    int e = blockIdx.x * blockDim.x + threadIdx.x;
    if (e >= E) return;
    int pos = atomicAdd(&cursor[dst[e]], 1);
    e_se[pos] = make_int2(src[e], __float_as_int(ea[e]));
}

// ---------------------------------------------------------------------------
// Per-layer src-projection: P[n] = { h[n]@Wf[64:128] , h[n]@Ws[64:128] }
// interleaved float2 per dim. Fully unrolled, float4 row loads.
// ---------------------------------------------------------------------------
__global__ __launch_bounds__(256) void proj_kernel(
    const float* __restrict__ h,
    const float* __restrict__ Wf, const float* __restrict__ Ws,
    float2* __restrict__ P)
{
    int t = blockIdx.x * 256 + threadIdx.x;
    int n = t >> 6;
    int d = t & 63;
    if (n >= GN) return;
    const float4* __restrict__ row4 = (const float4*)(h + (size_t)n * 64);
    const float* __restrict__ WfP = Wf + 64 * 64;   // rows 64..127
    const float* __restrict__ WsP = Ws + 64 * 64;
    float pf = 0.f, ps = 0.f;
#pragma unroll
    for (int c = 0; c < 16; ++c) {
        float4 v = row4[c];
#pragma unroll
        for (int i = 0; i < 4; ++i) {
            float hk = (i == 0) ? v.x : (i == 1) ? v.y : (i == 2) ? v.z : v.w;
            pf = fmaf(hk, WfP[(c * 4 + i) * 64 + d], pf);
            ps = fmaf(hk, WsP[(c * 4 + i) * 64 + d], ps);
        }
    }
    P[(size_t)n * 64 + d] = make_float2(pf, ps);
}

// ---------------------------------------------------------------------------
// CGConv edge pass, linearized. One 64-lane wave per node, lane = dim.
//   base (inline): q = bias + h[n]@W[0:64]   (both gates, fully unrolled)
//   per edge:      x = q + P[src] + ea*W[128];  agg += sigmoid(xF)*softplus(xS)
//   epilogue:      hout = relu(h + agg/deg)
// ---------------------------------------------------------------------------
__global__ __launch_bounds__(256) void edge_kernel(
    const float* __restrict__ h, const int* __restrict__ rowptr,
    const int2* __restrict__ e_se,
    const float2* __restrict__ P,
    const float* __restrict__ Wf, const float* __restrict__ bfv,
    const float* __restrict__ Ws, const float* __restrict__ bsv,
    float* __restrict__ hout)
{
    int n = blockIdx.x * 4 + (threadIdx.x >> 6);
    int d = threadIdx.x & 63;
    if (n >= GN) return;

    // inline dst-projection (weight streams L1-resident)
    const float4* __restrict__ row4 = (const float4*)(h + (size_t)n * 64);
    float qf = bfv[d], qs = bsv[d];
#pragma unroll
    for (int c = 0; c < 16; ++c) {
        float4 v = row4[c];
#pragma unroll
        for (int i = 0; i < 4; ++i) {
            float hk = (i == 0) ? v.x : (i == 1) ? v.y : (i == 2) ? v.z : v.w;
            qf = fmaf(hk, Wf[(c * 4 + i) * 64 + d], qf);
            qs = fmaf(hk, Ws[(c * 4 + i) * 64 + d], qs);
        }
    }
    float wf = Wf[128 * 64 + d];
    float ws = Ws[128 * 64 + d];

    int rb = rowptr[n], re = rowptr[n + 1];
    float agg = 0.f;
#pragma unroll 4
    for (int p = rb; p < re; ++p) {
        int2 se = e_se[p];         // wave-uniform 8B load
        int s = se.x;
        float ea = __int_as_float(se.y);
        float2 pv = P[(size_t)s * 64 + d];   // gathered, coalesced in d
        float xF = fmaf(ea, wf, qf + pv.x);
        float xS = fmaf(ea, ws, qs + pv.y);
        float sig = __builtin_amdgcn_rcpf(1.f + __expf(-xF));
        float t = __expf(-fabsf(xS));
        float sp = fmaxf(xS, 0.f) + __logf(1.f + t);
        agg = fmaf(sig, sp, agg);
    }

    float inv = 1.f / (float)max(re - rb, 1);
    size_t idx = (size_t)n * 64 + d;
    hout[idx] = fmaxf(h[idx] + agg * inv, 0.f);
}

// ---------------------------------------------------------------------------
// Graph segment starts: bm sorted; gstart[b] = first node of graph b.
// ---------------------------------------------------------------------------
__global__ __launch_bounds__(256) void gstart_kernel(
    const int* __restrict__ bm, int* __restrict__ gstart, int N)
{
    int i = blockIdx.x * blockDim.x + threadIdx.x;
    if (i >= N) return;
    int b = bm[i];
    int prev = (i == 0) ? -1 : bm[i - 1];
    for (int g = prev + 1; g <= b; ++g) gstart[g] = i;
    if (i == N - 1)
        for (int g = b + 1; g <= GB; ++g) gstart[g] = N;
}

// ---------------------------------------------------------------------------
// Segmented mean pool: one block per graph, no atomics.
// ---------------------------------------------------------------------------
__global__ __launch_bounds__(256) void pool_seg_kernel(
    const float* __restrict__ h, const int* __restrict__ gstart,
    float* __restrict__ g)
{
    int b = blockIdx.x;
    int s = gstart[b], e = gstart[b + 1];
    int d = threadIdx.x & 63;
    int w = threadIdx.x >> 6;
    float acc = 0.f;
    for (int n = s + w; n < e; n += 4)
        acc += h[(size_t)n * 64 + d];
    __shared__ float lds[256];
    lds[threadIdx.x] = acc;
    __syncthreads();
    if (w == 0) {
        acc = lds[d] + lds[64 + d] + lds[128 + d] + lds[192 + d];
        g[b * 64 + d] = acc / fmaxf((float)(e - s), 1.f);
    }
}

__global__ __launch_bounds__(128) void final_kernel(
    const float* __restrict__ g, const float* __restrict__ Wf,
    const float* __restrict__ bf, float* __restrict__ out, int B)
{
    int b = blockIdx.x * blockDim.x + threadIdx.x;
    if (b >= B) return;
    float acc = bf[0];
#pragma unroll
    for (int k = 0; k < 64; ++k)
        acc = fmaf(g[(size_t)b * 64 + k], Wf[k], acc);
    out[b] = acc;
}

extern "C" void kernel_launch(void* const* d_in, const int* in_sizes, int n_in,
                              void* d_out, int out_size, void* d_ws, size_t ws_size,
                              hipStream_t stream)
{
    const float* X      = (const float*)d_in[0];
    const int*   eidx   = (const int*)d_in[1];
    const float* ea     = (const float*)d_in[3];
    const int*   bm     = (const int*)d_in[4];
    const float* pre_W0 = (const float*)d_in[5];
    const float* pre_b0 = (const float*)d_in[6];
    const float* pre_W1 = (const float*)d_in[7];
    const float* pre_b1 = (const float*)d_in[8];
    const float* pre_W2 = (const float*)d_in[9];
    const float* pre_b2 = (const float*)d_in[10];
    const float* cg_Wf  = (const float*)d_in[11];
    const float* cg_bf  = (const float*)d_in[12];
    const float* cg_Ws  = (const float*)d_in[13];
    const float* cg_bs  = (const float*)d_in[14];
    const float* post_W0 = (const float*)d_in[15];
    const float* post_b0 = (const float*)d_in[16];
    const float* post_W1 = (const float*)d_in[17];
    const float* post_b1 = (const float*)d_in[18];
    const float* post_W2 = (const float*)d_in[19];
    const float* post_b2 = (const float*)d_in[20];
    const float* post_Wf = (const float*)d_in[21];
    const float* post_bf = (const float*)d_in[22];

    const int* src = eidx;
    const int* dst = eidx + GE;

    // ---- workspace carve-up ----
    const size_t N64 = (size_t)GN * 64;
    float* hA    = (float*)d_ws;          // N*64
    float* hB    = hA + N64;              // N*64
    float2* P    = (float2*)(hB + N64);   // N*64 float2
    int* deg_i   = (int*)(P + N64);       // N
    int* iscan   = deg_i + GN;            // N
    int* bsum    = iscan + GN;            // 128
    int* boff    = bsum + 128;            // 128
    int* rowptr  = boff + 128;            // N+1
    int* cursor  = rowptr + GN + 1;       // N
    int2* e_se   = (int2*)(cursor + GN);  // E int2 (8B-aligned: offset even)
    int* gstart  = (int*)(e_se + GE);     // B+1
    float* g0    = (float*)(gstart + GB + 1); // B*64
    float* g1    = g0 + GB * 64;          // B*64

    const int TPB = 256;
    int gridE  = (GE + TPB - 1) / TPB;
    int gridN  = (GN + TPB - 1) / TPB;
    int gridND = ((GN * 64) + TPB - 1) / TPB;  // 25000
    int scanBlocks = (GN + 1023) / 1024;       // 98

    // pre-GC MLP: X(F)->hA, hA->hB, hB->hA
    mlp92_kernel<<<gridND, TPB, 0, stream>>>(X,  pre_W0, pre_b0, hA, GN);
    mlp64_kernel<<<gridND, TPB, 0, stream>>>(hA, pre_W1, pre_b1, hB, GN);
    mlp64_kernel<<<gridND, TPB, 0, stream>>>(hB, pre_W2, pre_b2, hA, GN);

    // degree + CSR build
    hipMemsetAsync(deg_i, 0, GN * sizeof(int), stream);
    deg_kernel<<<gridE, TPB, 0, stream>>>(dst, deg_i, GE);
    scanA_kernel<<<scanBlocks, 1024, 0, stream>>>(deg_i, iscan, bsum, GN);
    scanB_kernel<<<1, 128, 0, stream>>>(bsum, boff, scanBlocks);
    scanC_kernel<<<gridN, TPB, 0, stream>>>(iscan, boff, deg_i, rowptr, cursor, GN);
    escatter_kernel<<<gridE, TPB, 0, stream>>>(src, dst, ea, cursor, e_se, GE);

    // graph segment starts (bm sorted)
    gstart_kernel<<<gridN, TPB, 0, stream>>>(bm, gstart, GN);

    // CGConv layers (ping-pong hA <-> hB)
    float* hin = hA; float* hout = hB;
    for (int l = 0; l < GL; ++l) {
        const float* Wf = cg_Wf + (size_t)l * GZ * GD;
        const float* Ws = cg_Ws + (size_t)l * GZ * GD;
        proj_kernel<<<gridND, TPB, 0, stream>>>(hin, Wf, Ws, P);
        edge_kernel<<<gridND, TPB, 0, stream>>>(
            hin, rowptr, e_se, P,
            Wf, cg_bf + (size_t)l * GD,
            Ws, cg_bs + (size_t)l * GD,
            hout);
        float* t = hin; hin = hout; hout = t;
    }
    // after 3 layers result is in hin

    // segmented mean pool (no atomics)
    pool_seg_kernel<<<GB, TPB, 0, stream>>>(hin, gstart, g0);

    // post-GC MLP
    mlp64_kernel<<<(GB * 64 + TPB - 1) / TPB, TPB, 0, stream>>>(g0, post_W0, post_b0, g1, GB);
    mlp64_kernel<<<(GB * 64 + TPB - 1) / TPB, TPB, 0, stream>>>(g1, post_W1, post_b1, g0, GB);
    mlp64_kernel<<<(GB * 64 + TPB - 1) / TPB, TPB, 0, stream>>>(g0, post_W2, post_b2, g1, GB);
    final_kernel<<<1, 128, 0, stream>>>(g1, post_Wf, post_bf, (float*)d_out, GB);
}

// Round 6
// 1557.377 us; speedup vs baseline: 8.6536x; 1.0438x over previous
//
#include <hip/hip_runtime.h>
#include <hip/hip_bf16.h>
#include <math.h>

// Problem constants (fixed by the reference)
#define GN 100000   // nodes
#define GE 1200000  // edges
#define GB 128      // graphs
#define GF 92       // raw features
#define GD 64       // hidden dim
#define GL 3        // CGConv layers
#define GZ 129      // 2*D+1

// round-to-nearest-even fp32 -> bf16 (returned in low 16 bits)
__device__ __forceinline__ unsigned int f2bf_rne(float x)
{
    unsigned int u = __float_as_uint(x);
    u += 0x7fffu + ((u >> 16) & 1u);
    return u >> 16;
}

// ---------------------------------------------------------------------------
// Dense layer, K=92. Rows are 368B (16B-aligned) -> 23 float4 loads.
// thread=(node,d); W reads coalesced, L1-resident.
// ---------------------------------------------------------------------------
__global__ __launch_bounds__(256) void mlp92_kernel(
    const float* __restrict__ in, const float* __restrict__ W,
    const float* __restrict__ b, float* __restrict__ out, int N)
{
    int t = blockIdx.x * 256 + threadIdx.x;
    int n = t >> 6;
    int d = t & 63;
    if (n >= N) return;
    const float4* __restrict__ row4 = (const float4*)(in + (size_t)n * GF);
    float acc = b[d];
#pragma unroll
    for (int c = 0; c < 23; ++c) {
        float4 v = row4[c];
        acc = fmaf(v.x, W[(c * 4 + 0) * 64 + d], acc);
        acc = fmaf(v.y, W[(c * 4 + 1) * 64 + d], acc);
        acc = fmaf(v.z, W[(c * 4 + 2) * 64 + d], acc);
        acc = fmaf(v.w, W[(c * 4 + 3) * 64 + d], acc);
    }
    out[(size_t)n * 64 + d] = fmaxf(acc, 0.f);
}

// ---------------------------------------------------------------------------
// Dense layer, K=64 (rows 256B-aligned -> float4 loads, full unroll).
// ---------------------------------------------------------------------------
__global__ __launch_bounds__(256) void mlp64_kernel(
    const float* __restrict__ in, const float* __restrict__ W,
    const float* __restrict__ b, float* __restrict__ out, int N)
{
    int t = blockIdx.x * 256 + threadIdx.x;
    int n = t >> 6;
    int d = t & 63;
    if (n >= N) return;
    const float4* __restrict__ row4 = (const float4*)(in + (size_t)n * 64);
    float acc = b[d];
#pragma unroll
    for (int c = 0; c < 16; ++c) {
        float4 v = row4[c];
        acc = fmaf(v.x, W[(c * 4 + 0) * 64 + d], acc);
        acc = fmaf(v.y, W[(c * 4 + 1) * 64 + d], acc);
        acc = fmaf(v.z, W[(c * 4 + 2) * 64 + d], acc);
        acc = fmaf(v.w, W[(c * 4 + 3) * 64 + d], acc);
    }
    out[(size_t)n * 64 + d] = fmaxf(acc, 0.f);
}

// ---------------------------------------------------------------------------
// In-degree histogram (int)
// ---------------------------------------------------------------------------
__global__ __launch_bounds__(256) void deg_kernel(
    const int* __restrict__ dst, int* __restrict__ deg, int E)
{
    int e = blockIdx.x * blockDim.x + threadIdx.x;
    if (e < E) atomicAdd(&deg[dst[e]], 1);
}

// ---------------------------------------------------------------------------
// Three-phase exclusive scan over deg -> rowptr, cursor
// ---------------------------------------------------------------------------
__global__ __launch_bounds__(1024) void scanA_kernel(
    const int* __restrict__ deg, int* __restrict__ iscan,
    int* __restrict__ bsum, int N)
{
    __shared__ int lds[1024];
    int tid = threadIdx.x;
    int gid = blockIdx.x * 1024 + tid;
    int v = (gid < N) ? deg[gid] : 0;
    lds[tid] = v; __syncthreads();
    for (int off = 1; off < 1024; off <<= 1) {
        int t = (tid >= off) ? lds[tid - off] : 0;
        __syncthreads();
        lds[tid] += t;
        __syncthreads();
    }
    if (gid < N) iscan[gid] = lds[tid];
    if (tid == 1023) bsum[blockIdx.x] = lds[1023];
}

__global__ __launch_bounds__(128) void scanB_kernel(
    const int* __restrict__ bsum, int* __restrict__ boff, int nb)
{
    __shared__ int lds[128];
    int t = threadIdx.x;
    int v = (t < nb) ? bsum[t] : 0;
    lds[t] = v; __syncthreads();
    for (int off = 1; off < 128; off <<= 1) {
        int u = (t >= off) ? lds[t - off] : 0;
        __syncthreads();
        lds[t] += u;
        __syncthreads();
    }
    if (t < nb) boff[t] = lds[t] - v;  // exclusive
}

__global__ __launch_bounds__(256) void scanC_kernel(
    const int* __restrict__ iscan, const int* __restrict__ boff,
    const int* __restrict__ deg,
    int* __restrict__ rowptr, int* __restrict__ cursor, int N)
{
    int i = blockIdx.x * blockDim.x + threadIdx.x;
    if (i >= N) return;
    int incl = iscan[i] + boff[i >> 10];
    rowptr[i + 1] = incl;
    cursor[i] = incl - deg[i];
    if (i == 0) rowptr[0] = 0;
}

// ---------------------------------------------------------------------------
// Edge scatter into CSR order, packed (src, ea) int2
// ---------------------------------------------------------------------------
__global__ __launch_bounds__(256) void escatter_kernel(
    const int* __restrict__ src, const int* __restrict__ dst,
    const float* __restrict__ ea, int* __restrict__ cursor,
    int2* __restrict__ e_se, int E)
{
    int e = blockIdx.x * blockDim.x + threadIdx.x;
    if (e >= E) return;
    int pos = atomicAdd(&cursor[dst[e]], 1);
    e_se[pos] = make_int2(src[e], __float_as_int(ea[e]));
}

// ---------------------------------------------------------------------------
// Per-layer src-projection, packed bf16: P[n][d] = pack(bf16(h@Wf[64:128]),
// bf16(h@Ws[64:128])). Edge gather becomes one dword per lane (256 B/row).
// ---------------------------------------------------------------------------
__global__ __launch_bounds__(256) void proj_kernel(
    const float* __restrict__ h,
    const float* __restrict__ Wf, const float* __restrict__ Ws,
    unsigned int* __restrict__ P)
{
    int t = blockIdx.x * 256 + threadIdx.x;
    int n = t >> 6;
    int d = t & 63;
    if (n >= GN) return;
    const float4* __restrict__ row4 = (const float4*)(h + (size_t)n * 64);
    const float* __restrict__ WfP = Wf + 64 * 64;   // rows 64..127
    const float* __restrict__ WsP = Ws + 64 * 64;
    float pf = 0.f, ps = 0.f;
#pragma unroll
    for (int c = 0; c < 16; ++c) {
        float4 v = row4[c];
#pragma unroll
        for (int i = 0; i < 4; ++i) {
            float hk = (i == 0) ? v.x : (i == 1) ? v.y : (i == 2) ? v.z : v.w;
            pf = fmaf(hk, WfP[(c * 4 + i) * 64 + d], pf);
            ps = fmaf(hk, WsP[(c * 4 + i) * 64 + d], ps);
        }
    }
    P[(size_t)n * 64 + d] = f2bf_rne(pf) | (f2bf_rne(ps) << 16);
}

// ---------------------------------------------------------------------------
// CGConv edge pass, linearized. One 64-lane wave per node, lane = dim.
//   base (inline): q = bias + h[n]@W[0:64]   (both gates, fully unrolled)
//   per edge:      x = q + unpack(P[src]) + ea*W[128]
//                  agg += sigmoid(xF)*softplus(xS)
//   epilogue:      hout = relu(h + agg/deg)
// ---------------------------------------------------------------------------
__global__ __launch_bounds__(256) void edge_kernel(
    const float* __restrict__ h, const int* __restrict__ rowptr,
    const int2* __restrict__ e_se,
    const unsigned int* __restrict__ P,
    const float* __restrict__ Wf, const float* __restrict__ bfv,
    const float* __restrict__ Ws, const float* __restrict__ bsv,
    float* __restrict__ hout)
{
    int n = blockIdx.x * 4 + (threadIdx.x >> 6);
    int d = threadIdx.x & 63;
    if (n >= GN) return;

    // inline dst-projection (weight streams L1-resident)
    const float4* __restrict__ row4 = (const float4*)(h + (size_t)n * 64);
    float qf = bfv[d], qs = bsv[d];
#pragma unroll
    for (int c = 0; c < 16; ++c) {
        float4 v = row4[c];
#pragma unroll
        for (int i = 0; i < 4; ++i) {
            float hk = (i == 0) ? v.x : (i == 1) ? v.y : (i == 2) ? v.z : v.w;
            qf = fmaf(hk, Wf[(c * 4 + i) * 64 + d], qf);
            qs = fmaf(hk, Ws[(c * 4 + i) * 64 + d], qs);
        }
    }
    float wf = Wf[128 * 64 + d];
    float ws = Ws[128 * 64 + d];

    int rb = rowptr[n], re = rowptr[n + 1];
    float agg = 0.f;
#pragma unroll 8
    for (int p = rb; p < re; ++p) {
        int2 se = e_se[p];         // wave-uniform 8B load
        int s = se.x;
        float ea = __int_as_float(se.y);
        unsigned int pv = P[(size_t)s * 64 + d];   // gathered dword
        float pf = __uint_as_float(pv << 16);
        float psv = __uint_as_float(pv & 0xffff0000u);
        float xF = fmaf(ea, wf, qf + pf);
        float xS = fmaf(ea, ws, qs + psv);
        float sig = __builtin_amdgcn_rcpf(1.f + __expf(-xF));
        float t = __expf(-fabsf(xS));
        float sp = fmaxf(xS, 0.f) + __logf(1.f + t);
        agg = fmaf(sig, sp, agg);
    }

    float inv = 1.f / (float)max(re - rb, 1);
    size_t idx = (size_t)n * 64 + d;
    hout[idx] = fmaxf(h[idx] + agg * inv, 0.f);
}

// ---------------------------------------------------------------------------
// Graph segment starts: bm sorted; gstart[b] = first node of graph b.
// ---------------------------------------------------------------------------
__global__ __launch_bounds__(256) void gstart_kernel(
    const int* __restrict__ bm, int* __restrict__ gstart, int N)
{
    int i = blockIdx.x * blockDim.x + threadIdx.x;
    if (i >= N) return;
    int b = bm[i];
    int prev = (i == 0) ? -1 : bm[i - 1];
    for (int g = prev + 1; g <= b; ++g) gstart[g] = i;
    if (i == N - 1)
        for (int g = b + 1; g <= GB; ++g) gstart[g] = N;
}

// ---------------------------------------------------------------------------
// Segmented mean pool: one block per graph, no atomics.
// ---------------------------------------------------------------------------
__global__ __launch_bounds__(256) void pool_seg_kernel(
    const float* __restrict__ h, const int* __restrict__ gstart,
    float* __restrict__ g)
{
    int b = blockIdx.x;
    int s = gstart[b], e = gstart[b + 1];
    int d = threadIdx.x & 63;
    int w = threadIdx.x >> 6;
    float acc = 0.f;
    for (int n = s + w; n < e; n += 4)
        acc += h[(size_t)n * 64 + d];
    __shared__ float lds[256];
    lds[threadIdx.x] = acc;
    __syncthreads();
    if (w == 0) {
        acc = lds[d] + lds[64 + d] + lds[128 + d] + lds[192 + d];
        g[b * 64 + d] = acc / fmaxf((float)(e - s), 1.f);
    }
}

__global__ __launch_bounds__(128) void final_kernel(
    const float* __restrict__ g, const float* __restrict__ Wf,
    const float* __restrict__ bf, float* __restrict__ out, int B)
{
    int b = blockIdx.x * blockDim.x + threadIdx.x;
    if (b >= B) return;
    float acc = bf[0];
#pragma unroll
    for (int k = 0; k < 64; ++k)
        acc = fmaf(g[(size_t)b * 64 + k], Wf[k], acc);
    out[b] = acc;
}

extern "C" void kernel_launch(void* const* d_in, const int* in_sizes, int n_in,
                              void* d_out, int out_size, void* d_ws, size_t ws_size,
                              hipStream_t stream)
{
    const float* X      = (const float*)d_in[0];
    const int*   eidx   = (const int*)d_in[1];
    const float* ea     = (const float*)d_in[3];
    const int*   bm     = (const int*)d_in[4];
    const float* pre_W0 = (const float*)d_in[5];
    const float* pre_b0 = (const float*)d_in[6];
    const float* pre_W1 = (const float*)d_in[7];
    const float* pre_b1 = (const float*)d_in[8];
    const float* pre_W2 = (const float*)d_in[9];
    const float* pre_b2 = (const float*)d_in[10];
    const float* cg_Wf  = (const float*)d_in[11];
    const float* cg_bf  = (const float*)d_in[12];
    const float* cg_Ws  = (const float*)d_in[13];
    const float* cg_bs  = (const float*)d_in[14];
    const float* post_W0 = (const float*)d_in[15];
    const float* post_b0 = (const float*)d_in[16];
    const float* post_W1 = (const float*)d_in[17];
    const float* post_b1 = (const float*)d_in[18];
    const float* post_W2 = (const float*)d_in[19];
    const float* post_b2 = (const float*)d_in[20];
    const float* post_Wf = (const float*)d_in[21];
    const float* post_bf = (const float*)d_in[22];

    const int* src = eidx;
    const int* dst = eidx + GE;

    // ---- workspace carve-up ----
    const size_t N64 = (size_t)GN * 64;
    float* hA    = (float*)d_ws;            // N*64
    float* hB    = hA + N64;                // N*64
    unsigned int* P = (unsigned int*)(hB + N64);  // N*64 packed bf16x2
    int* deg_i   = (int*)(P + N64);         // N
    int* iscan   = deg_i + GN;              // N
    int* bsum    = iscan + GN;              // 128
    int* boff    = bsum + 128;              // 128
    int* rowptr  = boff + 128;              // N+1
    int* cursor  = rowptr + GN + 1;         // N
    int2* e_se   = (int2*)(cursor + GN);    // E int2
    int* gstart  = (int*)(e_se + GE);       // B+1
    float* g0    = (float*)(gstart + GB + 1); // B*64
    float* g1    = g0 + GB * 64;            // B*64

    const int TPB = 256;
    int gridE  = (GE + TPB - 1) / TPB;
    int gridN  = (GN + TPB - 1) / TPB;
    int gridND = ((GN * 64) + TPB - 1) / TPB;  // 25000
    int scanBlocks = (GN + 1023) / 1024;       // 98

    // pre-GC MLP: X(F)->hA, hA->hB, hB->hA
    mlp92_kernel<<<gridND, TPB, 0, stream>>>(X,  pre_W0, pre_b0, hA, GN);
    mlp64_kernel<<<gridND, TPB, 0, stream>>>(hA, pre_W1, pre_b1, hB, GN);
    mlp64_kernel<<<gridND, TPB, 0, stream>>>(hB, pre_W2, pre_b2, hA, GN);

    // degree + CSR build
    hipMemsetAsync(deg_i, 0, GN * sizeof(int), stream);
    deg_kernel<<<gridE, TPB, 0, stream>>>(dst, deg_i, GE);
    scanA_kernel<<<scanBlocks, 1024, 0, stream>>>(deg_i, iscan, bsum, GN);
    scanB_kernel<<<1, 128, 0, stream>>>(bsum, boff, scanBlocks);
    scanC_kernel<<<gridN, TPB, 0, stream>>>(iscan, boff, deg_i, rowptr, cursor, GN);
    escatter_kernel<<<gridE, TPB, 0, stream>>>(src, dst, ea, cursor, e_se, GE);

    // graph segment starts (bm sorted)
    gstart_kernel<<<gridN, TPB, 0, stream>>>(bm, gstart, GN);

    // CGConv layers (ping-pong hA <-> hB)
    float* hin = hA; float* hout = hB;
    for (int l = 0; l < GL; ++l) {
        const float* Wf = cg_Wf + (size_t)l * GZ * GD;
        const float* Ws = cg_Ws + (size_t)l * GZ * GD;
        proj_kernel<<<gridND, TPB, 0, stream>>>(hin, Wf, Ws, P);
        edge_kernel<<<gridND, TPB, 0, stream>>>(
            hin, rowptr, e_se, P,
            Wf, cg_bf + (size_t)l * GD,
            Ws, cg_bs + (size_t)l * GD,
            hout);
        float* t = hin; hin = hout; hout = t;
    }
    // after 3 layers result is in hin

    // segmented mean pool (no atomics)
    pool_seg_kernel<<<GB, TPB, 0, stream>>>(hin, gstart, g0);

    // post-GC MLP
    mlp64_kernel<<<(GB * 64 + TPB - 1) / TPB, TPB, 0, stream>>>(g0, post_W0, post_b0, g1, GB);
    mlp64_kernel<<<(GB * 64 + TPB - 1) / TPB, TPB, 0, stream>>>(g1, post_W1, post_b1, g0, GB);
    mlp64_kernel<<<(GB * 64 + TPB - 1) / TPB, TPB, 0, stream>>>(g0, post_W2, post_b2, g1, GB);
    final_kernel<<<1, 128, 0, stream>>>(g1, post_Wf, post_bf, (float*)d_out, GB);
}

// Round 7
// 1383.905 us; speedup vs baseline: 9.7383x; 1.1253x over previous
//
#include <hip/hip_runtime.h>
#include <hip/hip_bf16.h>
#include <math.h>

// Problem constants (fixed by the reference)
#define GN 100000   // nodes
#define GE 1200000  // edges
#define GB 128      // graphs
#define GF 92       // raw features
#define GD 64       // hidden dim
#define GL 3        // CGConv layers
#define GZ 129      // 2*D+1

// round-to-nearest-even fp32 -> bf16 (returned in low 16 bits)
__device__ __forceinline__ unsigned int f2bf_rne(float x)
{
    unsigned int u = __float_as_uint(x);
    u += 0x7fffu + ((u >> 16) & 1u);
    return u >> 16;
}

// ---------------------------------------------------------------------------
// Fused pre-MLP (3 layers) + P0 projection. One wave per node, lane = dim.
// Layer chaining via __shfl broadcasts (all 64 dims live in the wave).
// Epilogue also emits P0 = pack(bf16(h@Wf0[64:128]), bf16(h@Ws0[64:128])).
// ---------------------------------------------------------------------------
__global__ __launch_bounds__(256) void premlp_kernel(
    const float* __restrict__ X,
    const float* __restrict__ W0, const float* __restrict__ b0,
    const float* __restrict__ W1, const float* __restrict__ b1,
    const float* __restrict__ W2, const float* __restrict__ b2,
    const float* __restrict__ WfN, const float* __restrict__ WsN,
    float* __restrict__ hout, unsigned int* __restrict__ Pout, int N)
{
    int t = blockIdx.x * 256 + threadIdx.x;
    int n = t >> 6;
    int d = t & 63;
    if (n >= N) return;

    // layer 0: K=92, rows 368B (16B-aligned) -> 23 float4 broadcast loads
    const float4* __restrict__ row4 = (const float4*)(X + (size_t)n * GF);
    float acc = b0[d];
#pragma unroll
    for (int c = 0; c < 23; ++c) {
        float4 v = row4[c];
        acc = fmaf(v.x, W0[(c * 4 + 0) * 64 + d], acc);
        acc = fmaf(v.y, W0[(c * 4 + 1) * 64 + d], acc);
        acc = fmaf(v.z, W0[(c * 4 + 2) * 64 + d], acc);
        acc = fmaf(v.w, W0[(c * 4 + 3) * 64 + d], acc);
    }
    float h = fmaxf(acc, 0.f);

    // layer 1 (shuffle-chained)
    acc = b1[d];
#pragma unroll
    for (int k = 0; k < 64; ++k)
        acc = fmaf(__shfl(h, k, 64), W1[k * 64 + d], acc);
    h = fmaxf(acc, 0.f);

    // layer 2
    acc = b2[d];
#pragma unroll
    for (int k = 0; k < 64; ++k)
        acc = fmaf(__shfl(h, k, 64), W2[k * 64 + d], acc);
    h = fmaxf(acc, 0.f);

    hout[(size_t)n * 64 + d] = h;

    // P0 projection (next CGConv layer's src half)
    float pf = 0.f, ps = 0.f;
#pragma unroll
    for (int k = 0; k < 64; ++k) {
        float hk = __shfl(h, k, 64);
        pf = fmaf(hk, WfN[k * 64 + d], pf);
        ps = fmaf(hk, WsN[k * 64 + d], ps);
    }
    Pout[(size_t)n * 64 + d] = f2bf_rne(pf) | (f2bf_rne(ps) << 16);
}

// ---------------------------------------------------------------------------
// In-degree histogram (int)
// ---------------------------------------------------------------------------
__global__ __launch_bounds__(256) void deg_kernel(
    const int* __restrict__ dst, int* __restrict__ deg, int E)
{
    int e = blockIdx.x * blockDim.x + threadIdx.x;
    if (e < E) atomicAdd(&deg[dst[e]], 1);
}

// ---------------------------------------------------------------------------
// Three-phase exclusive scan over deg -> rowptr, cursor
// ---------------------------------------------------------------------------
__global__ __launch_bounds__(1024) void scanA_kernel(
    const int* __restrict__ deg, int* __restrict__ iscan,
    int* __restrict__ bsum, int N)
{
    __shared__ int lds[1024];
    int tid = threadIdx.x;
    int gid = blockIdx.x * 1024 + tid;
    int v = (gid < N) ? deg[gid] : 0;
    lds[tid] = v; __syncthreads();
    for (int off = 1; off < 1024; off <<= 1) {
        int t = (tid >= off) ? lds[tid - off] : 0;
        __syncthreads();
        lds[tid] += t;
        __syncthreads();
    }
    if (gid < N) iscan[gid] = lds[tid];
    if (tid == 1023) bsum[blockIdx.x] = lds[1023];
}

__global__ __launch_bounds__(128) void scanB_kernel(
    const int* __restrict__ bsum, int* __restrict__ boff, int nb)
{
    __shared__ int lds[128];
    int t = threadIdx.x;
    int v = (t < nb) ? bsum[t] : 0;
    lds[t] = v; __syncthreads();
    for (int off = 1; off < 128; off <<= 1) {
        int u = (t >= off) ? lds[t - off] : 0;
        __syncthreads();
        lds[t] += u;
        __syncthreads();
    }
    if (t < nb) boff[t] = lds[t] - v;  // exclusive
}

__global__ __launch_bounds__(256) void scanC_kernel(
    const int* __restrict__ iscan, const int* __restrict__ boff,
    const int* __restrict__ deg,
    int* __restrict__ rowptr, int* __restrict__ cursor, int N)
{
    int i = blockIdx.x * blockDim.x + threadIdx.x;
    if (i >= N) return;
    int incl = iscan[i] + boff[i >> 10];
    rowptr[i + 1] = incl;
    cursor[i] = incl - deg[i];
    if (i == 0) rowptr[0] = 0;
}

// ---------------------------------------------------------------------------
// Edge scatter into CSR order, packed (src, ea) int2
// ---------------------------------------------------------------------------
__global__ __launch_bounds__(256) void escatter_kernel(
    const int* __restrict__ src, const int* __restrict__ dst,
    const float* __restrict__ ea, int* __restrict__ cursor,
    int2* __restrict__ e_se, int E)
{
    int e = blockIdx.x * blockDim.x + threadIdx.x;
    if (e >= E) return;
    int pos = atomicAdd(&cursor[dst[e]], 1);
    e_se[pos] = make_int2(src[e], __float_as_int(ea[e]));
}

// ---------------------------------------------------------------------------
// CGConv edge pass, linearized, with optional next-layer P fusion.
// One wave per node, lane = dim.
//   base (inline): q = bias + h[n]@W[0:64]   (both gates, fully unrolled)
//   per edge:      x = q + unpack(P[src]) + ea*W[128]
//                  agg += sigmoid(xF)*softplus(xS)
//   epilogue:      hnew = relu(h + agg/deg); store; if WITH_P also emit
//                  P_next = pack(bf16(hnew@WfN), bf16(hnew@WsN)) via shuffles.
// ---------------------------------------------------------------------------
template<bool WITH_P>
__global__ __launch_bounds__(256) void edge_kernel(
    const float* __restrict__ h, const int* __restrict__ rowptr,
    const int2* __restrict__ e_se,
    const unsigned int* __restrict__ P,
    const float* __restrict__ Wf, const float* __restrict__ bfv,
    const float* __restrict__ Ws, const float* __restrict__ bsv,
    const float* __restrict__ WfN, const float* __restrict__ WsN,
    float* __restrict__ hout, unsigned int* __restrict__ Pout)
{
    int n = blockIdx.x * 4 + (threadIdx.x >> 6);   // grid exactly covers GN
    int d = threadIdx.x & 63;

    // inline dst-projection (weight streams L1-resident)
    const float4* __restrict__ row4 = (const float4*)(h + (size_t)n * 64);
    float qf = bfv[d], qs = bsv[d];
#pragma unroll
    for (int c = 0; c < 16; ++c) {
        float4 v = row4[c];
#pragma unroll
        for (int i = 0; i < 4; ++i) {
            float hk = (i == 0) ? v.x : (i == 1) ? v.y : (i == 2) ? v.z : v.w;
            qf = fmaf(hk, Wf[(c * 4 + i) * 64 + d], qf);
            qs = fmaf(hk, Ws[(c * 4 + i) * 64 + d], qs);
        }
    }
    float wf = Wf[128 * 64 + d];
    float ws = Ws[128 * 64 + d];

    int rb = rowptr[n], re = rowptr[n + 1];
    float agg = 0.f;
#pragma unroll 8
    for (int p = rb; p < re; ++p) {
        int2 se = e_se[p];         // wave-uniform 8B load
        int s = se.x;
        float ea = __int_as_float(se.y);
        unsigned int pv = P[(size_t)s * 64 + d];   // gathered dword
        float pf = __uint_as_float(pv << 16);
        float psv = __uint_as_float(pv & 0xffff0000u);
        float xF = fmaf(ea, wf, qf + pf);
        float xS = fmaf(ea, ws, qs + psv);
        float sig = __builtin_amdgcn_rcpf(1.f + __expf(-xF));
        float t = __expf(-fabsf(xS));
        float sp = fmaxf(xS, 0.f) + __logf(1.f + t);
        agg = fmaf(sig, sp, agg);
    }

    float inv = 1.f / (float)max(re - rb, 1);
    size_t idx = (size_t)n * 64 + d;
    float hnew = fmaxf(h[idx] + agg * inv, 0.f);
    hout[idx] = hnew;

    if (WITH_P) {
        float pf = 0.f, ps = 0.f;
#pragma unroll
        for (int k = 0; k < 64; ++k) {
            float hk = __shfl(hnew, k, 64);
            pf = fmaf(hk, WfN[k * 64 + d], pf);
            ps = fmaf(hk, WsN[k * 64 + d], ps);
        }
        Pout[idx] = f2bf_rne(pf) | (f2bf_rne(ps) << 16);
    }
}

// ---------------------------------------------------------------------------
// Graph segment starts: bm sorted; gstart[b] = first node of graph b.
// ---------------------------------------------------------------------------
__global__ __launch_bounds__(256) void gstart_kernel(
    const int* __restrict__ bm, int* __restrict__ gstart, int N)
{
    int i = blockIdx.x * blockDim.x + threadIdx.x;
    if (i >= N) return;
    int b = bm[i];
    int prev = (i == 0) ? -1 : bm[i - 1];
    for (int g = prev + 1; g <= b; ++g) gstart[g] = i;
    if (i == N - 1)
        for (int g = b + 1; g <= GB; ++g) gstart[g] = N;
}

// ---------------------------------------------------------------------------
// Segmented mean pool: one block per graph, no atomics.
// ---------------------------------------------------------------------------
__global__ __launch_bounds__(256) void pool_seg_kernel(
    const float* __restrict__ h, const int* __restrict__ gstart,
    float* __restrict__ g)
{
    int b = blockIdx.x;
    int s = gstart[b], e = gstart[b + 1];
    int d = threadIdx.x & 63;
    int w = threadIdx.x >> 6;
    float acc = 0.f;
    for (int n = s + w; n < e; n += 4)
        acc += h[(size_t)n * 64 + d];
    __shared__ float lds[256];
    lds[threadIdx.x] = acc;
    __syncthreads();
    if (w == 0) {
        acc = lds[d] + lds[64 + d] + lds[128 + d] + lds[192 + d];
        g[b * 64 + d] = acc / fmaxf((float)(e - s), 1.f);
    }
}

// ---------------------------------------------------------------------------
// Fused post-MLP (3 relu layers, shuffle-chained) + final dot + bias.
// One wave per graph; butterfly reduce for the final projection.
// ---------------------------------------------------------------------------
__global__ __launch_bounds__(256) void postmlp_kernel(
    const float* __restrict__ g,
    const float* __restrict__ W0, const float* __restrict__ b0,
    const float* __restrict__ W1, const float* __restrict__ b1,
    const float* __restrict__ W2, const float* __restrict__ b2,
    const float* __restrict__ Wfin, const float* __restrict__ bfin,
    float* __restrict__ out)
{
    int b = blockIdx.x * 4 + (threadIdx.x >> 6);   // 32 blocks x 4 waves = 128
    int d = threadIdx.x & 63;
    float h = g[(size_t)b * 64 + d];

    float acc = b0[d];
#pragma unroll
    for (int k = 0; k < 64; ++k)
        acc = fmaf(__shfl(h, k, 64), W0[k * 64 + d], acc);
    h = fmaxf(acc, 0.f);

    acc = b1[d];
#pragma unroll
    for (int k = 0; k < 64; ++k)
        acc = fmaf(__shfl(h, k, 64), W1[k * 64 + d], acc);
    h = fmaxf(acc, 0.f);

    acc = b2[d];
#pragma unroll
    for (int k = 0; k < 64; ++k)
        acc = fmaf(__shfl(h, k, 64), W2[k * 64 + d], acc);
    h = fmaxf(acc, 0.f);

    float v = h * Wfin[d];
#pragma unroll
    for (int off = 32; off >= 1; off >>= 1)
        v += __shfl_xor(v, off, 64);
    if (d == 0) out[b] = v + bfin[0];
}

extern "C" void kernel_launch(void* const* d_in, const int* in_sizes, int n_in,
                              void* d_out, int out_size, void* d_ws, size_t ws_size,
                              hipStream_t stream)
{
    const float* X      = (const float*)d_in[0];
    const int*   eidx   = (const int*)d_in[1];
    const float* ea     = (const float*)d_in[3];
    const int*   bm     = (const int*)d_in[4];
    const float* pre_W0 = (const float*)d_in[5];
    const float* pre_b0 = (const float*)d_in[6];
    const float* pre_W1 = (const float*)d_in[7];
    const float* pre_b1 = (const float*)d_in[8];
    const float* pre_W2 = (const float*)d_in[9];
    const float* pre_b2 = (const float*)d_in[10];
    const float* cg_Wf  = (const float*)d_in[11];
    const float* cg_bf  = (const float*)d_in[12];
    const float* cg_Ws  = (const float*)d_in[13];
    const float* cg_bs  = (const float*)d_in[14];
    const float* post_W0 = (const float*)d_in[15];
    const float* post_b0 = (const float*)d_in[16];
    const float* post_W1 = (const float*)d_in[17];
    const float* post_b1 = (const float*)d_in[18];
    const float* post_W2 = (const float*)d_in[19];
    const float* post_b2 = (const float*)d_in[20];
    const float* post_Wf = (const float*)d_in[21];
    const float* post_bf = (const float*)d_in[22];

    const int* src = eidx;
    const int* dst = eidx + GE;

    // ---- workspace carve-up ----
    const size_t N64 = (size_t)GN * 64;
    float* hA    = (float*)d_ws;            // N*64
    float* hB    = hA + N64;                // N*64
    unsigned int* P = (unsigned int*)(hB + N64);  // N*64 packed bf16x2
    int* deg_i   = (int*)(P + N64);         // N
    int* iscan   = deg_i + GN;              // N
    int* bsum    = iscan + GN;              // 128
    int* boff    = bsum + 128;              // 128
    int* rowptr  = boff + 128;              // N+1
    int* cursor  = rowptr + GN + 1;         // N
    int2* e_se   = (int2*)(cursor + GN);    // E int2
    int* gstart  = (int*)(e_se + GE);       // B+1
    float* g0    = (float*)(gstart + GB + 1); // B*64

    const int TPB = 256;
    int gridE  = (GE + TPB - 1) / TPB;
    int gridN  = (GN + TPB - 1) / TPB;
    int gridND = ((GN * 64) + TPB - 1) / TPB;  // 25000
    int scanBlocks = (GN + 1023) / 1024;       // 98

    // per-layer weight pointers (src halves for P fusion)
    const float* Wf0 = cg_Wf;                       // layer 0
    const float* Ws0 = cg_Ws;
    const float* Wf1 = cg_Wf + (size_t)1 * GZ * GD;
    const float* Ws1 = cg_Ws + (size_t)1 * GZ * GD;
    const float* Wf2 = cg_Wf + (size_t)2 * GZ * GD;
    const float* Ws2 = cg_Ws + (size_t)2 * GZ * GD;

    // fused pre-MLP + P0
    premlp_kernel<<<gridND, TPB, 0, stream>>>(
        X, pre_W0, pre_b0, pre_W1, pre_b1, pre_W2, pre_b2,
        Wf0 + 64 * 64, Ws0 + 64 * 64, hA, P, GN);

    // degree + CSR build
    hipMemsetAsync(deg_i, 0, GN * sizeof(int), stream);
    deg_kernel<<<gridE, TPB, 0, stream>>>(dst, deg_i, GE);
    scanA_kernel<<<scanBlocks, 1024, 0, stream>>>(deg_i, iscan, bsum, GN);
    scanB_kernel<<<1, 128, 0, stream>>>(bsum, boff, scanBlocks);
    scanC_kernel<<<gridN, TPB, 0, stream>>>(iscan, boff, deg_i, rowptr, cursor, GN);
    escatter_kernel<<<gridE, TPB, 0, stream>>>(src, dst, ea, cursor, e_se, GE);

    // graph segment starts (bm sorted)
    gstart_kernel<<<gridN, TPB, 0, stream>>>(bm, gstart, GN);

    // CGConv layers: edge0 (emits P1), edge1 (emits P2), edge2 (no P)
    edge_kernel<true><<<gridND, TPB, 0, stream>>>(
        hA, rowptr, e_se, P,
        Wf0, cg_bf, Ws0, cg_bs,
        Wf1 + 64 * 64, Ws1 + 64 * 64, hB, P);
    edge_kernel<true><<<gridND, TPB, 0, stream>>>(
        hB, rowptr, e_se, P,
        Wf1, cg_bf + GD, Ws1, cg_bs + GD,
        Wf2 + 64 * 64, Ws2 + 64 * 64, hA, P);
    edge_kernel<false><<<gridND, TPB, 0, stream>>>(
        hA, rowptr, e_se, P,
        Wf2, cg_bf + 2 * GD, Ws2, cg_bs + 2 * GD,
        nullptr, nullptr, hB, nullptr);

    // segmented mean pool (no atomics)
    pool_seg_kernel<<<GB, TPB, 0, stream>>>(hB, gstart, g0);

    // fused post-MLP + final projection
    postmlp_kernel<<<GB / 4, TPB, 0, stream>>>(
        g0, post_W0, post_b0, post_W1, post_b1, post_W2, post_b2,
        post_Wf, post_bf, (float*)d_out);
}